// Round 4
// baseline (498.731 us; speedup 1.0000x reference)
//
#include <hip/hip_runtime.h>
#include <math.h>

#define NEG_SLOPE 0.2f
#define FIN 128
#define H1 8
#define F1 64   // HEADS1*HID
#define F2 32   // OUT2

#define SHIFT 5
#define BW 32          // dsts per bucket
#define CAPL 2048      // LDS edge slots per bucket (mean ~1056; padded max ~1300)
#define CAP_G 1408     // static pk slots per bucket (mean+11sigma)
#define NBMAX 4096

// two-pass radix partition (write-coalescing fix for the 7x write amplification)
#define SB_SHIFT 11            // 2048 nodes per super-bucket = 64 final buckets
#define NSBMAX 64              // supports N <= 131072
#define P_CHUNK 2048           // edges per partition block
#define BPS 35                 // pass-2 blocks per SB
#define SBCAP (BPS * P_CHUNK)  // slots per SB in sbdata

typedef unsigned short ushort_t;
typedef unsigned int uint_t;

#define LO16(u) __uint_as_float((u) << 16)
#define HI16(u) __uint_as_float((u) & 0xffff0000u)

// fold across the 8 edge slots (lane bits 3..5)
#define FOLDQ(x) { x += __shfl_xor(x, 8, 64); x += __shfl_xor(x, 16, 64); x += __shfl_xor(x, 32, 64); }
// fold across all 64 lanes
#define FOLD64(x) { x += __shfl_xor(x, 1, 64); x += __shfl_xor(x, 2, 64); x += __shfl_xor(x, 4, 64); \
                    x += __shfl_xor(x, 8, 64); x += __shfl_xor(x, 16, 64); x += __shfl_xor(x, 32, 64); }

static __device__ __forceinline__ ushort_t f2bf(float f) {
    uint_t u = __float_as_uint(f);
    u = (u + 0x7FFFu + ((u >> 16) & 1u)) >> 16; // RNE
    return (ushort_t)u;
}
// pack {A=exp(e), B=exp(0.2e)} as bf16x2: A in low 16, B in high 16
static __device__ __forceinline__ uint_t packAB(float e) {
    return (uint_t)f2bf(__expf(e)) | ((uint_t)f2bf(__expf(NEG_SLOPE * e)) << 16);
}

// ---------------- Layer-1 GEMM: h1 = x @ W1 (bf16 out), fused exp-tables -----
__global__ void gemm1_kernel(const float* __restrict__ x, const float* __restrict__ W1,
                             const float* __restrict__ a_src, const float* __restrict__ a_dst,
                             ushort_t* __restrict__ h1, uint_t* __restrict__ sp,
                             float* __restrict__ ed, int N) {
    __shared__ float xs[16][FIN]; // 8 KB
    int tid = threadIdx.x;
    int n0 = blockIdx.x * 16;
    for (int i = tid; i < 16 * FIN; i += 256) {
        int nn = n0 + (i >> 7);
        xs[i >> 7][i & 127] = (nn < N) ? x[(size_t)nn * FIN + (i & 127)] : 0.f;
    }
    __syncthreads();
    int wv = tid >> 6, j = tid & 63;
    int nb = wv << 2;
    float a0 = 0.f, a1 = 0.f, a2 = 0.f, a3 = 0.f;
#pragma unroll 2
    for (int k = 0; k < FIN; k += 4) {
        float w0 = W1[(k + 0) * F1 + j];
        float w1 = W1[(k + 1) * F1 + j];
        float w2 = W1[(k + 2) * F1 + j];
        float w3 = W1[(k + 3) * F1 + j];
        float4 x0 = *(const float4*)&xs[nb + 0][k];
        float4 x1 = *(const float4*)&xs[nb + 1][k];
        float4 x2 = *(const float4*)&xs[nb + 2][k];
        float4 x3 = *(const float4*)&xs[nb + 3][k];
        a0 = fmaf(x0.x, w0, fmaf(x0.y, w1, fmaf(x0.z, w2, fmaf(x0.w, w3, a0))));
        a1 = fmaf(x1.x, w0, fmaf(x1.y, w1, fmaf(x1.z, w2, fmaf(x1.w, w3, a1))));
        a2 = fmaf(x2.x, w0, fmaf(x2.y, w1, fmaf(x2.z, w2, fmaf(x2.w, w3, a2))));
        a3 = fmaf(x3.x, w0, fmaf(x3.y, w1, fmaf(x3.z, w2, fmaf(x3.w, w3, a3))));
    }
    float as = a_src[j], ad = a_dst[j];
    float av[4] = {a0, a1, a2, a3};
#pragma unroll
    for (int t = 0; t < 4; ++t) {
        int n = n0 + nb + t;
        if (n >= N) break;
        h1[(size_t)n * F1 + j] = f2bf(av[t]);
        float vs = av[t] * as;
        float vd = av[t] * ad;
#pragma unroll
        for (int off = 4; off >= 1; off >>= 1) {
            vs += __shfl_down(vs, off, 8);
            vd += __shfl_down(vd, off, 8);
        }
        if ((j & 7) == 0) {
            sp[n * H1 + (j >> 3)] = packAB(vs);
            ed[n * H1 + (j >> 3)] = vd;
        }
    }
}

// ---------------- init: counters, dummy node (padding target) ----------------
__global__ void zerob_kernel(int* __restrict__ bcnt, int* __restrict__ boff,
                             int NB, float* __restrict__ pooled, int capg,
                             int* __restrict__ sbcnt, int nsb,
                             uint_t* __restrict__ sp1, ushort_t* __restrict__ h1,
                             int* __restrict__ ctrs, int N) {
    int t = blockIdx.x * blockDim.x + threadIdx.x;
    int stride = gridDim.x * blockDim.x;
    for (int i = t; i < NB; i += stride) {
        bcnt[i] = 0;
        if (capg) boff[i] = i * capg;
    }
    for (int i = t; i < nsb; i += stride) sbcnt[i] = 0;
    if (t < H1) sp1[(size_t)N * H1 + t] = 0u;              // dummy: weight == 0
    if (t >= 8 && t < 8 + F1) h1[(size_t)N * F1 + (t - 8)] = 0; // dummy: finite row
    if (t == 72) pooled[0] = 0.f;
    if (t == 73) ctrs[0] = 0;
    if (t == 74) ctrs[1] = 0;
}

// ---------------- Pass 1: partition edges into super-buckets (coalesced) -----
__global__ void __launch_bounds__(256, 4)
part1_kernel(const int* __restrict__ ei, int E, int N,
             int* __restrict__ sbcnt, uint_t* __restrict__ sbdata) {
    __shared__ int hist[NSBMAX];
    __shared__ int loff[NSBMAX];
    __shared__ int lcur[NSBMAX];
    __shared__ int gb[NSBMAX];
    __shared__ uint_t buf[P_CHUNK];
    __shared__ unsigned char sbarr[P_CHUNK];
    int tid = threadIdx.x;
    int NSB = (N + ((1 << SB_SHIFT) - 1)) >> SB_SHIFT;
    for (int i = tid; i < NSB; i += 256) hist[i] = 0;
    __syncthreads();
    int EN = E + N;
    int base = blockIdx.x * P_CHUNK;
    int m = EN - base; if (m > P_CHUNK) m = P_CHUNK;
    int t0 = base + tid * 8;
    int s[8], d[8];
    bool fast = (t0 + 8 <= E) && ((E & 3) == 0);
    if (fast) {
        int4 a = *(const int4*)&ei[t0];
        int4 b = *(const int4*)&ei[t0 + 4];
        s[0]=a.x; s[1]=a.y; s[2]=a.z; s[3]=a.w; s[4]=b.x; s[5]=b.y; s[6]=b.z; s[7]=b.w;
        int4 c = *(const int4*)&ei[E + t0];
        int4 e2 = *(const int4*)&ei[E + t0 + 4];
        d[0]=c.x; d[1]=c.y; d[2]=c.z; d[3]=c.w; d[4]=e2.x; d[5]=e2.y; d[6]=e2.z; d[7]=e2.w;
    } else {
#pragma unroll
        for (int r = 0; r < 8; ++r) {
            int t = t0 + r;
            if (t < EN) {
                if (t < E) { s[r] = ei[t]; d[r] = ei[E + t]; }
                else       { s[r] = d[r] = t - E; }
            } else d[r] = -1;
        }
    }
#pragma unroll
    for (int r = 0; r < 8; ++r)
        if (d[r] >= 0) atomicAdd(&hist[d[r] >> SB_SHIFT], 1);
    __syncthreads();
    if (tid < 64) {
        int v = (tid < NSB) ? hist[tid] : 0;
        int e = v;
#pragma unroll
        for (int o = 1; o < 64; o <<= 1) {
            int u = __shfl_up(e, o, 64);
            if (tid >= o) e += u;
        }
        e -= v; // exclusive prefix
        if (tid < NSB) {
            loff[tid] = e;
            lcur[tid] = e;
            gb[tid] = v ? atomicAdd(&sbcnt[tid], v) : 0;
        }
    }
    __syncthreads();
#pragma unroll
    for (int r = 0; r < 8; ++r)
        if (d[r] >= 0) {
            int sb = d[r] >> SB_SHIFT;
            int pos = atomicAdd(&lcur[sb], 1);
            buf[pos] = ((uint_t)s[r] << SB_SHIFT) | (uint_t)(d[r] & ((1 << SB_SHIFT) - 1));
            sbarr[pos] = (unsigned char)sb;
        }
    __syncthreads();
    for (int i = tid; i < m; i += 256) {
        int sb = sbarr[i];
        int idx = gb[sb] + (i - loff[sb]);
        if (idx < SBCAP)
            sbdata[(size_t)sb * SBCAP + idx] = buf[i];
    }
}

// ---------------- Pass 2: scatter within SB to final pk buckets (coalesced) --
__global__ void __launch_bounds__(256, 4)
part2_kernel(const uint_t* __restrict__ sbdata, const int* __restrict__ sbcnt,
             int* __restrict__ bcnt, const int* __restrict__ boff,
             uint_t* __restrict__ pk) {
    __shared__ int hist[64];
    __shared__ int loff[64];
    __shared__ int lcur[64];
    __shared__ int gb[64];
    __shared__ uint_t buf[P_CHUNK];
    int tid = threadIdx.x;
    int sb = blockIdx.x / BPS;
    int base = (blockIdx.x % BPS) * P_CHUNK;
    int cnt = sbcnt[sb];
    if (cnt > SBCAP) cnt = SBCAP;
    if (base >= cnt) return;
    int m = cnt - base; if (m > P_CHUNK) m = P_CHUNK;
    if (tid < 64) hist[tid] = 0;
    __syncthreads();
    const uint_t* src = sbdata + (size_t)sb * SBCAP + base;
    uint_t v[8];
#pragma unroll
    for (int r = 0; r < 8; ++r) {
        int i = tid + r * 256; // coalesced strided read
        if (i < m) {
            v[r] = src[i];
            atomicAdd(&hist[(v[r] >> 5) & 63], 1);
        }
    }
    __syncthreads();
    if (tid < 64) {
        int c = hist[tid];
        int e = c;
#pragma unroll
        for (int o = 1; o < 64; o <<= 1) {
            int u = __shfl_up(e, o, 64);
            if (tid >= o) e += u;
        }
        e -= c;
        loff[tid] = e;
        lcur[tid] = e;
        int bucket = (sb << 6) + tid;
        gb[tid] = c ? (boff[bucket] + atomicAdd(&bcnt[bucket], c)) : 0;
    }
    __syncthreads();
#pragma unroll
    for (int r = 0; r < 8; ++r) {
        int i = tid + r * 256;
        if (i < m) {
            int lb = (v[r] >> 5) & 63;
            int pos = atomicAdd(&lcur[lb], 1);
            buf[pos] = v[r];
        }
    }
    __syncthreads();
    for (int i = tid; i < m; i += 256) {
        uint_t u = buf[i];
        int lb = (u >> 5) & 63;
        int idx = gb[lb] + (i - loff[lb]);
        pk[idx] = ((u >> SB_SHIFT) << SHIFT) | (u & (BW - 1));
    }
}

// ---- exact-CSR fallback path (used only when ws_size too small for static) --
__global__ void bhist_kernel(const int* __restrict__ ei, int E, int N,
                             int* __restrict__ bcnt, int NB) {
    __shared__ int h[NBMAX];
    int tid = threadIdx.x;
    for (int i = tid; i < NB; i += 256) h[i] = 0;
    __syncthreads();
    int EN = E + N;
    int chunk = (EN + gridDim.x - 1) / gridDim.x;
    int e0 = blockIdx.x * chunk;
    int e1 = e0 + chunk; if (e1 > EN) e1 = EN;
    for (int t = e0 + tid; t < e1; t += 256) {
        int d = (t < E) ? ei[E + t] : (t - E);
        atomicAdd(&h[d >> SHIFT], 1);
    }
    __syncthreads();
    for (int i = tid; i < NB; i += 256)
        if (h[i]) atomicAdd(&bcnt[i], h[i]);
}

__global__ void bscan_kernel(const int* __restrict__ bcnt, int NB,
                             int* __restrict__ boff, int* __restrict__ bcur) {
    int lane = threadIdx.x; // 0..63
    int chunk = (NB + 63) >> 6;
    int lo = lane * chunk;
    int hi = lo + chunk; if (hi > NB) hi = NB;
    int sum = 0;
    for (int i = lo; i < hi; ++i) sum += bcnt[i];
    int e = sum;
#pragma unroll
    for (int o = 1; o < 64; o <<= 1) {
        int v = __shfl_up(e, o, 64);
        if (lane >= o) e += v;
    }
    e -= sum;
    int run = e;
    for (int i = lo; i < hi; ++i) {
        int c = bcnt[i];
        boff[i] = run;
        bcur[i] = run;
        run += c;
    }
}

__global__ void bscat_kernel(const int* __restrict__ ei, int E, int N,
                             int* __restrict__ bcur, uint_t* __restrict__ pk, int NB) {
    __shared__ int lh[NBMAX];
    __shared__ int lc[NBMAX];
    int tid = threadIdx.x;
    for (int i = tid; i < NB; i += 256) lh[i] = 0;
    __syncthreads();
    int EN = E + N;
    int chunk = (EN + gridDim.x - 1) / gridDim.x;
    int e0 = blockIdx.x * chunk;
    int e1 = e0 + chunk; if (e1 > EN) e1 = EN;
    for (int t = e0 + tid; t < e1; t += 256) {
        int d = (t < E) ? ei[E + t] : (t - E);
        atomicAdd(&lh[d >> SHIFT], 1);
    }
    __syncthreads();
    for (int i = tid; i < NB; i += 256) {
        int c = lh[i];
        lc[i] = c ? atomicAdd(&bcur[i], c) : 0;
    }
    __syncthreads();
    for (int t = e0 + tid; t < e1; t += 256) {
        int s, d;
        if (t < E) { s = ei[t]; d = ei[E + t]; } else { s = d = t - E; }
        int pos = atomicAdd(&lc[d >> SHIFT], 1);
        pk[pos] = ((uint_t)s << SHIFT) | (uint_t)(d & (BW - 1));
    }
}

// ---------------- Layer-1 edge pass: persistent blocks, guard-free inner -----
// Lane L: slot q=L>>3 (8 edges in flight), head=L&7, channels c8=head*8 (uint4).
// Per-dst lists padded to x8 with dummy node N (sp==0 -> w==0 exactly).
__global__ void __launch_bounds__(256, 8)
edge1_gather(const int* __restrict__ bcnt, const int* __restrict__ boff,
             const uint_t* __restrict__ pk,
             const uint_t* __restrict__ sp, const float* __restrict__ ed,
             const ushort_t* __restrict__ h1, float* __restrict__ o1,
             int* __restrict__ ctr, int NB, int N) {
    int tid = threadIdx.x;
    int wv = tid >> 6;
    int L = tid & 63;
    int q = L >> 3;          // edge slot 0..7
    int head = L & 7;        // attention head == channel group
    int c8 = head << 3;      // channel base (8 channels = one uint4 of bf16)
    __shared__ int ldeg[BW], loff[BW], ldgp[BW], lcur[BW];
    __shared__ int lsrc[CAPL];
    __shared__ int sbk, stot;
    for (;;) {
        if (tid == 0) sbk = atomicAdd(ctr, 1);
        __syncthreads();
        int b = sbk;
        if (b >= NB) break;
        int d0 = b << SHIFT;
        int cnt = bcnt[b];
        int gbase = boff[b];
        if (cnt <= CAPL - 8 * BW - 8) {
            if (tid < BW) ldeg[tid] = 0;
            __syncthreads();
            for (int k = tid; k < cnt; k += 256) atomicAdd(&ldeg[pk[gbase + k] & (BW - 1)], 1);
            __syncthreads();
            if (tid < BW) {
                int v = ldeg[tid];
                int vp = (v + 7) & ~7;       // padded length
                int e = vp;
#pragma unroll
                for (int o = 1; o < BW; o <<= 1) {
                    int u = __shfl_up(e, o, 64);
                    if (tid >= o) e += u;
                }
                e -= vp;
                loff[tid] = e;
                lcur[tid] = e;
                ldgp[tid] = vp;
                if (tid == BW - 1) stot = e + vp;
            }
            __syncthreads();
            int tot = stot;
            for (int k = tid; k < tot + 8; k += 256) lsrc[k] = N;  // dummy fill (+guard)
            __syncthreads();
            for (int k = tid; k < cnt; k += 256) {
                uint_t v = pk[gbase + k];
                int pos = atomicAdd(&lcur[v & (BW - 1)], 1);
                lsrc[pos] = (int)(v >> SHIFT);
            }
            __syncthreads();
            for (int ld = wv * 8; ld < wv * 8 + 8; ++ld) {
                int d = d0 + ld;
                if (d >= N) break;
                int st = loff[ld], en = st + ldgp[ld];
                float edv = ed[d * H1 + head];
                float Ad = __expf(edv), Bd = __expf(NEG_SLOPE * edv);
                float a0=0.f,a1=0.f,a2=0.f,a3=0.f,a4=0.f,a5=0.f,a6=0.f,a7=0.f,ws=0.f;
                int s = lsrc[st + q];
                uint_t U = sp[s * H1 + head];
                uint4 V = *(const uint4*)(h1 + ((size_t)s << 6) + c8);
                for (int k = st; k < en; k += 8) {
                    int s2 = lsrc[k + 8 + q];          // safe: guard slots / next list
                    uint_t U2 = sp[s2 * H1 + head];
                    uint4 V2 = *(const uint4*)(h1 + ((size_t)s2 << 6) + c8);
                    float w = fmaxf(LO16(U) * Ad, HI16(U) * Bd);
                    a0 = fmaf(w, LO16(V.x), a0); a1 = fmaf(w, HI16(V.x), a1);
                    a2 = fmaf(w, LO16(V.y), a2); a3 = fmaf(w, HI16(V.y), a3);
                    a4 = fmaf(w, LO16(V.z), a4); a5 = fmaf(w, HI16(V.z), a5);
                    a6 = fmaf(w, LO16(V.w), a6); a7 = fmaf(w, HI16(V.w), a7);
                    ws += w;
                    U = U2; V = V2;
                }
                FOLDQ(a0); FOLDQ(a1); FOLDQ(a2); FOLDQ(a3);
                FOLDQ(a4); FOLDQ(a5); FOLDQ(a6); FOLDQ(a7); FOLDQ(ws);
                if (q == 0) {
                    float inv = 1.f / ws;
                    float4 r0; r0.x = a0*inv; r0.y = a1*inv; r0.z = a2*inv; r0.w = a3*inv;
                    float4 r1; r1.x = a4*inv; r1.y = a5*inv; r1.z = a6*inv; r1.w = a7*inv;
                    float* dp = o1 + (size_t)d * F1 + c8;
                    *(float4*)dp = r0;
                    *(float4*)(dp + 4) = r1;
                }
            }
        } else {
            // statistically unreachable fallback: masked whole-bucket scan
            for (int ld = wv * 8; ld < wv * 8 + 8; ++ld) {
                int d = d0 + ld;
                if (d >= N) break;
                float edv = ed[d * H1 + head];
                float Ad = __expf(edv), Bd = __expf(NEG_SLOPE * edv);
                float a0=0.f,a1=0.f,a2=0.f,a3=0.f,a4=0.f,a5=0.f,a6=0.f,a7=0.f,ws=0.f;
                for (int k0 = 0; k0 < cnt; k0 += 8) {
                    int idx = k0 + q;
                    bool ok = idx < cnt;
                    uint_t v = pk[gbase + (ok ? idx : 0)];
                    int s = (int)(v >> SHIFT);
                    bool mm = ok && ((int)(v & (BW - 1)) == ld);
                    uint_t U = sp[s * H1 + head];
                    uint4 V = *(const uint4*)(h1 + ((size_t)s << 6) + c8);
                    float w = mm ? fmaxf(LO16(U) * Ad, HI16(U) * Bd) : 0.f;
                    a0 = fmaf(w, LO16(V.x), a0); a1 = fmaf(w, HI16(V.x), a1);
                    a2 = fmaf(w, LO16(V.y), a2); a3 = fmaf(w, HI16(V.y), a3);
                    a4 = fmaf(w, LO16(V.z), a4); a5 = fmaf(w, HI16(V.z), a5);
                    a6 = fmaf(w, LO16(V.w), a6); a7 = fmaf(w, HI16(V.w), a7);
                    ws += w;
                }
                FOLDQ(a0); FOLDQ(a1); FOLDQ(a2); FOLDQ(a3);
                FOLDQ(a4); FOLDQ(a5); FOLDQ(a6); FOLDQ(a7); FOLDQ(ws);
                if (q == 0) {
                    float inv = 1.f / ws;
                    float4 r0; r0.x = a0*inv; r0.y = a1*inv; r0.z = a2*inv; r0.w = a3*inv;
                    float4 r1; r1.x = a4*inv; r1.y = a5*inv; r1.z = a6*inv; r1.w = a7*inv;
                    float* dp = o1 + (size_t)d * F1 + c8;
                    *(float4*)dp = r0;
                    *(float4*)(dp + 4) = r1;
                }
            }
        }
    }
}

// ---------------- Layer-2 GEMM: folds Wr projection -> 8-B record per node ---
// rec[n] = { packAB(e_src2), g = (a1@W2 row) . Wr }  (g in f32, no bf16 loss)
__global__ void gemm2_kernel(const float* __restrict__ o1, const float* __restrict__ b1,
                             const float* __restrict__ W2,
                             const float* __restrict__ a_src2, const float* __restrict__ a_dst2,
                             const float* __restrict__ Wr,
                             uint2* __restrict__ rec, float* __restrict__ ed2, int N) {
    if (blockIdx.x == 0 && threadIdx.x == 0) {
        uint2 z; z.x = 0u; z.y = 0u;
        rec[N] = z;                     // dummy node: w==0, g==0
    }
    int half = threadIdx.x >> 5;
    int n = blockIdx.x * 8 + half;
    int j = threadIdx.x & 31;
    __shared__ float a1s[8][F1];
    if (n < N) {
#pragma unroll
        for (int r = 0; r < 2; ++r) {
            int k = r * 32 + j;
            float v = o1[(size_t)n * F1 + k] + b1[k];
            a1s[half][k] = v > 0.f ? v : expm1f(v); // ELU
        }
    }
    __syncthreads();
    if (n >= N) return;
    float acc = 0.f;
#pragma unroll
    for (int k = 0; k < F1; ++k) acc = fmaf(a1s[half][k], W2[k * F2 + j], acc);
    float vs = acc * a_src2[j];
    float vd = acc * a_dst2[j];
    float vg = acc * Wr[j];
#pragma unroll
    for (int off = 16; off >= 1; off >>= 1) {
        vs += __shfl_down(vs, off, 32);
        vd += __shfl_down(vd, off, 32);
        vg += __shfl_down(vg, off, 32);
    }
    if (j == 0) {
        uint2 r; r.x = packAB(vs); r.y = __float_as_uint(vg);
        rec[n] = r;
        ed2[n] = vd;
    }
}

// ---------------- Layer-2 edge pass: scalar-projected gather -----------------
// Per edge: one 8-B record load {spAB, g}. Wave = 64 edges in parallel per dst.
__global__ void __launch_bounds__(256, 8)
edge2_gather(const int* __restrict__ bcnt, const int* __restrict__ boff,
             const uint_t* __restrict__ pk,
             const uint2* __restrict__ rec, const float* __restrict__ ed2,
             const float* __restrict__ b2, const float* __restrict__ Wr,
             float* __restrict__ pooled, int* __restrict__ ctr, int NB, int N) {
    int tid = threadIdx.x;
    int wv = tid >> 6;
    int L = tid & 63;
    __shared__ int ldeg[BW], loff[BW], ldgp[BW], lcur[BW];
    __shared__ int lsrc[CAPL];
    __shared__ int sbk, stot;
    __shared__ float ls[4];
    float t0 = (L < F2) ? b2[L] * Wr[L] : 0.f;
    FOLD64(t0);
    float b2w = t0;          // dot(b2, Wr), identical on all lanes
    float part = 0.f;
    for (;;) {
        if (tid == 0) sbk = atomicAdd(ctr, 1);
        __syncthreads();
        int b = sbk;
        if (b >= NB) break;
        int d0 = b << SHIFT;
        int cnt = bcnt[b];
        int gbase = boff[b];
        if (cnt <= CAPL - 8 * BW - 8) {
            if (tid < BW) ldeg[tid] = 0;
            __syncthreads();
            for (int k = tid; k < cnt; k += 256) atomicAdd(&ldeg[pk[gbase + k] & (BW - 1)], 1);
            __syncthreads();
            if (tid < BW) {
                int v = ldeg[tid];
                int vp = (v + 7) & ~7;
                int e = vp;
#pragma unroll
                for (int o = 1; o < BW; o <<= 1) {
                    int u = __shfl_up(e, o, 64);
                    if (tid >= o) e += u;
                }
                e -= vp;
                loff[tid] = e;
                lcur[tid] = e;
                ldgp[tid] = vp;
                if (tid == BW - 1) stot = e + vp;
            }
            __syncthreads();
            int tot = stot;
            for (int k = tid; k < tot + 8; k += 256) lsrc[k] = N;
            __syncthreads();
            for (int k = tid; k < cnt; k += 256) {
                uint_t v = pk[gbase + k];
                int pos = atomicAdd(&lcur[v & (BW - 1)], 1);
                lsrc[pos] = (int)(v >> SHIFT);
            }
            __syncthreads();
            for (int ld = wv * 8; ld < wv * 8 + 8; ++ld) {
                int d = d0 + ld;
                if (d >= N) break;
                int st = loff[ld], en = st + ldgp[ld];
                float edv = ed2[d];
                float Ad = __expf(edv), Bd = __expf(NEG_SLOPE * edv);
                float acc = 0.f, wsm = 0.f;
                for (int k = st; k < en; k += 64) {
                    int i = k + L;
                    bool ok = i < en;
                    int s = lsrc[ok ? i : st];
                    uint2 r = rec[s];
                    float w = ok ? fmaxf(LO16(r.x) * Ad, HI16(r.x) * Bd) : 0.f;
                    acc = fmaf(w, __uint_as_float(r.y), acc);
                    wsm += w;
                }
                FOLD64(acc); FOLD64(wsm);
                part += acc / wsm + b2w;   // identical on all lanes; lane 0 used below
            }
        } else {
            for (int ld = wv * 8; ld < wv * 8 + 8; ++ld) {
                int d = d0 + ld;
                if (d >= N) break;
                float edv = ed2[d];
                float Ad = __expf(edv), Bd = __expf(NEG_SLOPE * edv);
                float acc = 0.f, wsm = 0.f;
                for (int k0 = 0; k0 < cnt; k0 += 64) {
                    int i = k0 + L;
                    bool ok = i < cnt;
                    uint_t v = pk[gbase + (ok ? i : 0)];
                    int s = (int)(v >> SHIFT);
                    bool mm = ok && ((int)(v & (BW - 1)) == ld);
                    uint2 r = rec[s];
                    float w = mm ? fmaxf(LO16(r.x) * Ad, HI16(r.x) * Bd) : 0.f;
                    acc = fmaf(w, __uint_as_float(r.y), acc);
                    wsm += w;
                }
                FOLD64(acc); FOLD64(wsm);
                part += acc / wsm + b2w;
            }
        }
    }
    if (L == 0) ls[wv] = part;
    __syncthreads();
    if (tid == 0) atomicAdd(pooled, ls[0] + ls[1] + ls[2] + ls[3]);
}

__global__ void final_kernel(const float* __restrict__ pooled, const float* __restrict__ br,
                             float* __restrict__ out) {
    if (threadIdx.x == 0 && blockIdx.x == 0) out[0] = pooled[0] + br[0];
}

extern "C" void kernel_launch(void* const* d_in, const int* in_sizes, int n_in,
                              void* d_out, int out_size, void* d_ws, size_t ws_size,
                              hipStream_t stream) {
    const float* x    = (const float*)d_in[0];
    const int*   ei   = (const int*)d_in[1];
    const float* W1   = (const float*)d_in[2];
    const float* a_s1 = (const float*)d_in[3];
    const float* a_d1 = (const float*)d_in[4];
    const float* b1   = (const float*)d_in[5];
    const float* W2   = (const float*)d_in[6];
    const float* a_s2 = (const float*)d_in[7];
    const float* a_d2 = (const float*)d_in[8];
    const float* b2   = (const float*)d_in[9];
    const float* Wr   = (const float*)d_in[10];
    const float* br   = (const float*)d_in[11];
    float* out = (float*)d_out;

    int N = in_sizes[0] / FIN;
    int E = in_sizes[1] / 2;
    size_t n = (size_t)N;
    int NB = (N + BW - 1) >> SHIFT;
    int NSB = (N + ((1 << SB_SHIFT) - 1)) >> SB_SHIFT;

    // workspace layout (bytes); +1 dummy node row in sp1/h1 for padding
    char* ws = (char*)d_ws;
    float*    o1   = (float*)ws;                          // 256N
    uint_t*   sp1  = (uint_t*)(ws + n * 256);             // 32N + 32 (dummy row)
    float*    ed1  = (float*)(ws + n * 288 + 64);         // 32N
    ushort_t* h1   = (ushort_t*)(ws + n * 320 + 64);      // 128N + 128 (dummy row)
    uint_t*   pk   = (uint_t*)(ws + n * 448 + 256);
    size_t pk_static = (size_t)NB * CAP_G * 4;            // ~17.6 MB
    size_t pk_exact  = (size_t)(E + N) * 4;               // ~13.2 MB
    // sbdata overlays o1 (disjoint lifetimes)
    uint_t* sbdata = (uint_t*)ws;
    bool use_static = (NSB <= NSBMAX) &&
                      ((size_t)NSB * SBCAP * 4 <= n * 256) &&
                      (ws_size >= n * 448 + 256 + pk_static + (size_t)NBMAX * 16 +
                                  (size_t)NSBMAX * 4 + 64);
    char* tail = ws + n * 448 + 256 + (use_static ? pk_static : pk_exact);
    int*      bcnt  = (int*)tail;                         // NBMAX int
    int*      boff  = (int*)(tail + NBMAX * 4);           // NBMAX int
    int*      bcur  = (int*)(tail + NBMAX * 8);           // NBMAX int
    int*      sbcnt = (int*)(tail + NBMAX * 12);          // NSBMAX int
    float*  pooled  = (float*)(tail + NBMAX * 12 + NSBMAX * 4); // 1 f32
    int*      ctrs  = (int*)(tail + NBMAX * 12 + NSBMAX * 4 + 8); // 2 int
    // layer-2 overlays (dead after edge1): rec over h1, ed2 over ed1
    uint2* rec = (uint2*)h1;
    float* ed2 = ed1;

    int egrid = NB < 2048 ? NB : 2048;

    zerob_kernel<<<8, 256, 0, stream>>>(bcnt, boff, NB, pooled,
                                        use_static ? CAP_G : 0, sbcnt, NSB,
                                        sp1, h1, ctrs, N);
    if (use_static) {
        int EN = E + N;
        int G1 = (EN + P_CHUNK - 1) / P_CHUNK;
        part1_kernel<<<G1, 256, 0, stream>>>(ei, E, N, sbcnt, sbdata);
        part2_kernel<<<NSB * BPS, 256, 0, stream>>>(sbdata, sbcnt, bcnt, boff, pk);
        gemm1_kernel<<<(N + 15) / 16, 256, 0, stream>>>(x, W1, a_s1, a_d1, h1, sp1, ed1, N);
    } else {
        gemm1_kernel<<<(N + 15) / 16, 256, 0, stream>>>(x, W1, a_s1, a_d1, h1, sp1, ed1, N);
        bhist_kernel<<<256, 256, 0, stream>>>(ei, E, N, bcnt, NB);
        bscan_kernel<<<1, 64, 0, stream>>>(bcnt, NB, boff, bcur);
        bscat_kernel<<<256, 256, 0, stream>>>(ei, E, N, bcur, pk, NB);
    }
    edge1_gather<<<egrid, 256, 0, stream>>>(bcnt, boff, pk, sp1, ed1, h1, o1,
                                            ctrs + 0, NB, N);
    gemm2_kernel<<<(N + 7) / 8, 256, 0, stream>>>(o1, b1, W2, a_s2, a_d2, Wr, rec, ed2, N);
    edge2_gather<<<egrid, 256, 0, stream>>>(bcnt, boff, pk, rec, ed2, b2, Wr, pooled,
                                            ctrs + 1, NB, N);
    final_kernel<<<1, 64, 0, stream>>>(pooled, br, out);
}

// Round 6
// 458.695 us; speedup vs baseline: 1.0873x; 1.0873x over previous
//
#include <hip/hip_runtime.h>
#include <math.h>

#define NEG_SLOPE 0.2f
#define FIN 128
#define H1 8
#define F1 64   // HEADS1*HID
#define F2 32   // OUT2

#define SHIFT 5
#define BW 32          // dsts per bucket
#define CAPL 2048      // LDS edge slots per bucket (mean ~1056; padded max ~1300)
#define CAP_G 1408     // static pk slots per bucket (mean+11sigma)
#define NBMAX 4096

// two-pass radix partition (write-coalescing fix for the 7x write amplification)
#define SB_SHIFT 11            // 2048 nodes per super-bucket = 64 final buckets
#define NSBMAX 64              // supports N <= 131072
#define P_CHUNK 2048           // edges per partition block
#define BPS 35                 // pass-2 blocks per SB
#define SBCAP (BPS * P_CHUNK)  // slots per SB in sbdata

typedef unsigned short ushort_t;
typedef unsigned int uint_t;

#define LO16(u) __uint_as_float((u) << 16)
#define HI16(u) __uint_as_float((u) & 0xffff0000u)

// fold across the 8 edge slots (lane bits 3..5)
#define FOLDQ(x) { x += __shfl_xor(x, 8, 64); x += __shfl_xor(x, 16, 64); x += __shfl_xor(x, 32, 64); }
// fold across all 64 lanes
#define FOLD64(x) { x += __shfl_xor(x, 1, 64); x += __shfl_xor(x, 2, 64); x += __shfl_xor(x, 4, 64); \
                    x += __shfl_xor(x, 8, 64); x += __shfl_xor(x, 16, 64); x += __shfl_xor(x, 32, 64); }

static __device__ __forceinline__ ushort_t f2bf(float f) {
    uint_t u = __float_as_uint(f);
    u = (u + 0x7FFFu + ((u >> 16) & 1u)) >> 16; // RNE
    return (ushort_t)u;
}
// pack {A=exp(e), B=exp(0.2e)} as bf16x2: A in low 16, B in high 16
static __device__ __forceinline__ uint_t packAB(float e) {
    return (uint_t)f2bf(__expf(e)) | ((uint_t)f2bf(__expf(NEG_SLOPE * e)) << 16);
}

// ---------------- Layer-1 GEMM: h1 = x @ W1 (bf16 out), fused exp-tables -----
__global__ void gemm1_kernel(const float* __restrict__ x, const float* __restrict__ W1,
                             const float* __restrict__ a_src, const float* __restrict__ a_dst,
                             ushort_t* __restrict__ h1, uint_t* __restrict__ sp,
                             float* __restrict__ ed, int N) {
    __shared__ float xs[16][FIN]; // 8 KB
    int tid = threadIdx.x;
    int n0 = blockIdx.x * 16;
    for (int i = tid; i < 16 * FIN; i += 256) {
        int nn = n0 + (i >> 7);
        xs[i >> 7][i & 127] = (nn < N) ? x[(size_t)nn * FIN + (i & 127)] : 0.f;
    }
    __syncthreads();
    int wv = tid >> 6, j = tid & 63;
    int nb = wv << 2;
    float a0 = 0.f, a1 = 0.f, a2 = 0.f, a3 = 0.f;
#pragma unroll 2
    for (int k = 0; k < FIN; k += 4) {
        float w0 = W1[(k + 0) * F1 + j];
        float w1 = W1[(k + 1) * F1 + j];
        float w2 = W1[(k + 2) * F1 + j];
        float w3 = W1[(k + 3) * F1 + j];
        float4 x0 = *(const float4*)&xs[nb + 0][k];
        float4 x1 = *(const float4*)&xs[nb + 1][k];
        float4 x2 = *(const float4*)&xs[nb + 2][k];
        float4 x3 = *(const float4*)&xs[nb + 3][k];
        a0 = fmaf(x0.x, w0, fmaf(x0.y, w1, fmaf(x0.z, w2, fmaf(x0.w, w3, a0))));
        a1 = fmaf(x1.x, w0, fmaf(x1.y, w1, fmaf(x1.z, w2, fmaf(x1.w, w3, a1))));
        a2 = fmaf(x2.x, w0, fmaf(x2.y, w1, fmaf(x2.z, w2, fmaf(x2.w, w3, a2))));
        a3 = fmaf(x3.x, w0, fmaf(x3.y, w1, fmaf(x3.z, w2, fmaf(x3.w, w3, a3))));
    }
    float as = a_src[j], ad = a_dst[j];
    float av[4] = {a0, a1, a2, a3};
#pragma unroll
    for (int t = 0; t < 4; ++t) {
        int n = n0 + nb + t;
        if (n >= N) break;
        h1[(size_t)n * F1 + j] = f2bf(av[t]);
        float vs = av[t] * as;
        float vd = av[t] * ad;
#pragma unroll
        for (int off = 4; off >= 1; off >>= 1) {
            vs += __shfl_down(vs, off, 8);
            vd += __shfl_down(vd, off, 8);
        }
        if ((j & 7) == 0) {
            sp[n * H1 + (j >> 3)] = packAB(vs);
            ed[n * H1 + (j >> 3)] = vd;
        }
    }
}

// ---------------- init: counters, dummy node (padding target) ----------------
__global__ void zerob_kernel(int* __restrict__ bcnt, int* __restrict__ boff,
                             int NB, float* __restrict__ pooled, int capg,
                             int* __restrict__ sbcnt, int nsb,
                             uint_t* __restrict__ sp1, ushort_t* __restrict__ h1,
                             int* __restrict__ ctrs, int N) {
    int t = blockIdx.x * blockDim.x + threadIdx.x;
    int stride = gridDim.x * blockDim.x;
    for (int i = t; i < NB; i += stride) {
        bcnt[i] = 0;
        if (capg) boff[i] = i * capg;
    }
    for (int i = t; i < nsb; i += stride) sbcnt[i] = 0;
    if (t < H1) sp1[(size_t)N * H1 + t] = 0u;              // dummy: weight == 0
    if (t >= 8 && t < 8 + F1) h1[(size_t)N * F1 + (t - 8)] = 0; // dummy: finite row
    if (t == 72) pooled[0] = 0.f;
    if (t == 73) ctrs[0] = 0;
    if (t == 74) ctrs[1] = 0;
}

// ---------------- Pass 1: partition edges into super-buckets (coalesced) -----
__global__ void __launch_bounds__(256, 4)
part1_kernel(const int* __restrict__ ei, int E, int N,
             int* __restrict__ sbcnt, uint_t* __restrict__ sbdata) {
    __shared__ int hist[NSBMAX];
    __shared__ int loff[NSBMAX];
    __shared__ int lcur[NSBMAX];
    __shared__ int gb[NSBMAX];
    __shared__ uint_t buf[P_CHUNK];
    __shared__ unsigned char sbarr[P_CHUNK];
    int tid = threadIdx.x;
    int NSB = (N + ((1 << SB_SHIFT) - 1)) >> SB_SHIFT;
    for (int i = tid; i < NSB; i += 256) hist[i] = 0;
    __syncthreads();
    int EN = E + N;
    int base = blockIdx.x * P_CHUNK;
    int m = EN - base; if (m > P_CHUNK) m = P_CHUNK;
    int t0 = base + tid * 8;
    int s[8], d[8];
    bool fast = (t0 + 8 <= E) && ((E & 3) == 0);
    if (fast) {
        int4 a = *(const int4*)&ei[t0];
        int4 b = *(const int4*)&ei[t0 + 4];
        s[0]=a.x; s[1]=a.y; s[2]=a.z; s[3]=a.w; s[4]=b.x; s[5]=b.y; s[6]=b.z; s[7]=b.w;
        int4 c = *(const int4*)&ei[E + t0];
        int4 e2 = *(const int4*)&ei[E + t0 + 4];
        d[0]=c.x; d[1]=c.y; d[2]=c.z; d[3]=c.w; d[4]=e2.x; d[5]=e2.y; d[6]=e2.z; d[7]=e2.w;
    } else {
#pragma unroll
        for (int r = 0; r < 8; ++r) {
            int t = t0 + r;
            if (t < EN) {
                if (t < E) { s[r] = ei[t]; d[r] = ei[E + t]; }
                else       { s[r] = d[r] = t - E; }
            } else d[r] = -1;
        }
    }
#pragma unroll
    for (int r = 0; r < 8; ++r)
        if (d[r] >= 0) atomicAdd(&hist[d[r] >> SB_SHIFT], 1);
    __syncthreads();
    if (tid < 64) {
        int v = (tid < NSB) ? hist[tid] : 0;
        int e = v;
#pragma unroll
        for (int o = 1; o < 64; o <<= 1) {
            int u = __shfl_up(e, o, 64);
            if (tid >= o) e += u;
        }
        e -= v; // exclusive prefix
        if (tid < NSB) {
            loff[tid] = e;
            lcur[tid] = e;
            gb[tid] = v ? atomicAdd(&sbcnt[tid], v) : 0;
        }
    }
    __syncthreads();
#pragma unroll
    for (int r = 0; r < 8; ++r)
        if (d[r] >= 0) {
            int sb = d[r] >> SB_SHIFT;
            int pos = atomicAdd(&lcur[sb], 1);
            buf[pos] = ((uint_t)s[r] << SB_SHIFT) | (uint_t)(d[r] & ((1 << SB_SHIFT) - 1));
            sbarr[pos] = (unsigned char)sb;
        }
    __syncthreads();
    for (int i = tid; i < m; i += 256) {
        int sb = sbarr[i];
        int idx = gb[sb] + (i - loff[sb]);
        if (idx < SBCAP)
            sbdata[(size_t)sb * SBCAP + idx] = buf[i];
    }
}

// ---------------- Pass 2: scatter within SB to final pk buckets (coalesced) --
__global__ void __launch_bounds__(256, 4)
part2_kernel(const uint_t* __restrict__ sbdata, const int* __restrict__ sbcnt,
             int* __restrict__ bcnt, const int* __restrict__ boff,
             uint_t* __restrict__ pk) {
    __shared__ int hist[64];
    __shared__ int loff[64];
    __shared__ int lcur[64];
    __shared__ int gb[64];
    __shared__ uint_t buf[P_CHUNK];
    int tid = threadIdx.x;
    int sb = blockIdx.x / BPS;
    int base = (blockIdx.x % BPS) * P_CHUNK;
    int cnt = sbcnt[sb];
    if (cnt > SBCAP) cnt = SBCAP;
    if (base >= cnt) return;
    int m = cnt - base; if (m > P_CHUNK) m = P_CHUNK;
    if (tid < 64) hist[tid] = 0;
    __syncthreads();
    const uint_t* src = sbdata + (size_t)sb * SBCAP + base;
    uint_t v[8];
#pragma unroll
    for (int r = 0; r < 8; ++r) {
        int i = tid + r * 256; // coalesced strided read
        if (i < m) {
            v[r] = src[i];
            atomicAdd(&hist[(v[r] >> 5) & 63], 1);
        }
    }
    __syncthreads();
    if (tid < 64) {
        int c = hist[tid];
        int e = c;
#pragma unroll
        for (int o = 1; o < 64; o <<= 1) {
            int u = __shfl_up(e, o, 64);
            if (tid >= o) e += u;
        }
        e -= c;
        loff[tid] = e;
        lcur[tid] = e;
        int bucket = (sb << 6) + tid;
        gb[tid] = c ? (boff[bucket] + atomicAdd(&bcnt[bucket], c)) : 0;
    }
    __syncthreads();
#pragma unroll
    for (int r = 0; r < 8; ++r) {
        int i = tid + r * 256;
        if (i < m) {
            int lb = (v[r] >> 5) & 63;
            int pos = atomicAdd(&lcur[lb], 1);
            buf[pos] = v[r];
        }
    }
    __syncthreads();
    for (int i = tid; i < m; i += 256) {
        uint_t u = buf[i];
        int lb = (u >> 5) & 63;
        int idx = gb[lb] + (i - loff[lb]);
        pk[idx] = ((u >> SB_SHIFT) << SHIFT) | (u & (BW - 1));
    }
}

// ---- exact-CSR fallback path (used only when ws_size too small for static) --
__global__ void bhist_kernel(const int* __restrict__ ei, int E, int N,
                             int* __restrict__ bcnt, int NB) {
    __shared__ int h[NBMAX];
    int tid = threadIdx.x;
    for (int i = tid; i < NB; i += 256) h[i] = 0;
    __syncthreads();
    int EN = E + N;
    int chunk = (EN + gridDim.x - 1) / gridDim.x;
    int e0 = blockIdx.x * chunk;
    int e1 = e0 + chunk; if (e1 > EN) e1 = EN;
    for (int t = e0 + tid; t < e1; t += 256) {
        int d = (t < E) ? ei[E + t] : (t - E);
        atomicAdd(&h[d >> SHIFT], 1);
    }
    __syncthreads();
    for (int i = tid; i < NB; i += 256)
        if (h[i]) atomicAdd(&bcnt[i], h[i]);
}

__global__ void bscan_kernel(const int* __restrict__ bcnt, int NB,
                             int* __restrict__ boff, int* __restrict__ bcur) {
    int lane = threadIdx.x; // 0..63
    int chunk = (NB + 63) >> 6;
    int lo = lane * chunk;
    int hi = lo + chunk; if (hi > NB) hi = NB;
    int sum = 0;
    for (int i = lo; i < hi; ++i) sum += bcnt[i];
    int e = sum;
#pragma unroll
    for (int o = 1; o < 64; o <<= 1) {
        int v = __shfl_up(e, o, 64);
        if (lane >= o) e += v;
    }
    e -= sum;
    int run = e;
    for (int i = lo; i < hi; ++i) {
        int c = bcnt[i];
        boff[i] = run;
        bcur[i] = run;
        run += c;
    }
}

__global__ void bscat_kernel(const int* __restrict__ ei, int E, int N,
                             int* __restrict__ bcur, uint_t* __restrict__ pk, int NB) {
    __shared__ int lh[NBMAX];
    __shared__ int lc[NBMAX];
    int tid = threadIdx.x;
    for (int i = tid; i < NB; i += 256) lh[i] = 0;
    __syncthreads();
    int EN = E + N;
    int chunk = (EN + gridDim.x - 1) / gridDim.x;
    int e0 = blockIdx.x * chunk;
    int e1 = e0 + chunk; if (e1 > EN) e1 = EN;
    for (int t = e0 + tid; t < e1; t += 256) {
        int d = (t < E) ? ei[E + t] : (t - E);
        atomicAdd(&lh[d >> SHIFT], 1);
    }
    __syncthreads();
    for (int i = tid; i < NB; i += 256) {
        int c = lh[i];
        lc[i] = c ? atomicAdd(&bcur[i], c) : 0;
    }
    __syncthreads();
    for (int t = e0 + tid; t < e1; t += 256) {
        int s, d;
        if (t < E) { s = ei[t]; d = ei[E + t]; } else { s = d = t - E; }
        int pos = atomicAdd(&lc[d >> SHIFT], 1);
        pk[pos] = ((uint_t)s << SHIFT) | (uint_t)(d & (BW - 1));
    }
}

// ---------------- Layer-1 edge pass: persistent blocks, depth-2 pipeline -----
// Lane L: slot q=L>>3 (8 edges/group), head=L&7, channels c8=head*8 (uint4).
// Per-dst lists padded to x8 with dummy node N (sp==0 -> w==0 exactly).
// Depth-2 prefetch: 3 {sp,h1} load pairs in flight per lane.
__global__ void __launch_bounds__(256, 8)
edge1_gather(const int* __restrict__ bcnt, const int* __restrict__ boff,
             const uint_t* __restrict__ pk,
             const uint_t* __restrict__ sp, const float* __restrict__ ed,
             const ushort_t* __restrict__ h1, float* __restrict__ o1,
             int* __restrict__ ctr, int NB, int N) {
    int tid = threadIdx.x;
    int wv = tid >> 6;
    int L = tid & 63;
    int q = L >> 3;          // edge slot 0..7
    int head = L & 7;        // attention head == channel group
    int c8 = head << 3;      // channel base (8 channels = one uint4 of bf16)
    __shared__ int ldeg[BW], loff[BW], ldgp[BW], lcur[BW];
    __shared__ int lsrc[CAPL];
    __shared__ int sbk, stot;
    for (;;) {
        if (tid == 0) sbk = atomicAdd(ctr, 1);
        __syncthreads();
        int b = sbk;
        if (b >= NB) break;
        int d0 = b << SHIFT;
        int cnt = bcnt[b];
        int gbase = boff[b];
        if (cnt <= CAPL - 8 * BW - 16) {
            if (tid < BW) ldeg[tid] = 0;
            __syncthreads();
            for (int k = tid; k < cnt; k += 256) atomicAdd(&ldeg[pk[gbase + k] & (BW - 1)], 1);
            __syncthreads();
            if (tid < BW) {
                int v = ldeg[tid];
                int vp = (v + 7) & ~7;       // padded length
                int e = vp;
#pragma unroll
                for (int o = 1; o < BW; o <<= 1) {
                    int u = __shfl_up(e, o, 64);
                    if (tid >= o) e += u;
                }
                e -= vp;
                loff[tid] = e;
                lcur[tid] = e;
                ldgp[tid] = vp;
                if (tid == BW - 1) stot = e + vp;
            }
            __syncthreads();
            int tot = stot;
            for (int k = tid; k < tot + 16; k += 256) lsrc[k] = N;  // dummy fill (+guards)
            __syncthreads();
            for (int k = tid; k < cnt; k += 256) {
                uint_t v = pk[gbase + k];
                int pos = atomicAdd(&lcur[v & (BW - 1)], 1);
                lsrc[pos] = (int)(v >> SHIFT);
            }
            __syncthreads();
            for (int ld = wv * 8; ld < wv * 8 + 8; ++ld) {
                int d = d0 + ld;
                if (d >= N) break;
                int st = loff[ld], en = st + ldgp[ld];
                float edv = ed[d * H1 + head];
                float Ad = __expf(edv), Bd = __expf(NEG_SLOPE * edv);
                float a0=0.f,a1=0.f,a2=0.f,a3=0.f,a4=0.f,a5=0.f,a6=0.f,a7=0.f,ws=0.f;
                int sA = lsrc[st + q];
                uint_t UA = sp[sA * H1 + head];
                uint4 VA = *(const uint4*)(h1 + ((size_t)sA << 6) + c8);
                int sB = lsrc[st + 8 + q];
                uint_t UB = sp[sB * H1 + head];
                uint4 VB = *(const uint4*)(h1 + ((size_t)sB << 6) + c8);
                for (int k = st; k < en; k += 8) {
                    int sC = lsrc[k + 16 + q];         // safe: guard slots / next lists
                    uint_t UC = sp[sC * H1 + head];
                    uint4 VC = *(const uint4*)(h1 + ((size_t)sC << 6) + c8);
                    float w = fmaxf(LO16(UA) * Ad, HI16(UA) * Bd);
                    a0 = fmaf(w, LO16(VA.x), a0); a1 = fmaf(w, HI16(VA.x), a1);
                    a2 = fmaf(w, LO16(VA.y), a2); a3 = fmaf(w, HI16(VA.y), a3);
                    a4 = fmaf(w, LO16(VA.z), a4); a5 = fmaf(w, HI16(VA.z), a5);
                    a6 = fmaf(w, LO16(VA.w), a6); a7 = fmaf(w, HI16(VA.w), a7);
                    ws += w;
                    UA = UB; VA = VB;
                    UB = UC; VB = VC;
                }
                FOLDQ(a0); FOLDQ(a1); FOLDQ(a2); FOLDQ(a3);
                FOLDQ(a4); FOLDQ(a5); FOLDQ(a6); FOLDQ(a7); FOLDQ(ws);
                if (q == 0) {
                    float inv = 1.f / ws;
                    float4 r0; r0.x = a0*inv; r0.y = a1*inv; r0.z = a2*inv; r0.w = a3*inv;
                    float4 r1; r1.x = a4*inv; r1.y = a5*inv; r1.z = a6*inv; r1.w = a7*inv;
                    float* dp = o1 + (size_t)d * F1 + c8;
                    *(float4*)dp = r0;
                    *(float4*)(dp + 4) = r1;
                }
            }
        } else {
            // statistically unreachable fallback: masked whole-bucket scan
            for (int ld = wv * 8; ld < wv * 8 + 8; ++ld) {
                int d = d0 + ld;
                if (d >= N) break;
                float edv = ed[d * H1 + head];
                float Ad = __expf(edv), Bd = __expf(NEG_SLOPE * edv);
                float a0=0.f,a1=0.f,a2=0.f,a3=0.f,a4=0.f,a5=0.f,a6=0.f,a7=0.f,ws=0.f;
                for (int k0 = 0; k0 < cnt; k0 += 8) {
                    int idx = k0 + q;
                    bool ok = idx < cnt;
                    uint_t v = pk[gbase + (ok ? idx : 0)];
                    int s = (int)(v >> SHIFT);
                    bool mm = ok && ((int)(v & (BW - 1)) == ld);
                    uint_t U = sp[s * H1 + head];
                    uint4 V = *(const uint4*)(h1 + ((size_t)s << 6) + c8);
                    float w = mm ? fmaxf(LO16(U) * Ad, HI16(U) * Bd) : 0.f;
                    a0 = fmaf(w, LO16(V.x), a0); a1 = fmaf(w, HI16(V.x), a1);
                    a2 = fmaf(w, LO16(V.y), a2); a3 = fmaf(w, HI16(V.y), a3);
                    a4 = fmaf(w, LO16(V.z), a4); a5 = fmaf(w, HI16(V.z), a5);
                    a6 = fmaf(w, LO16(V.w), a6); a7 = fmaf(w, HI16(V.w), a7);
                    ws += w;
                }
                FOLDQ(a0); FOLDQ(a1); FOLDQ(a2); FOLDQ(a3);
                FOLDQ(a4); FOLDQ(a5); FOLDQ(a6); FOLDQ(a7); FOLDQ(ws);
                if (q == 0) {
                    float inv = 1.f / ws;
                    float4 r0; r0.x = a0*inv; r0.y = a1*inv; r0.z = a2*inv; r0.w = a3*inv;
                    float4 r1; r1.x = a4*inv; r1.y = a5*inv; r1.z = a6*inv; r1.w = a7*inv;
                    float* dp = o1 + (size_t)d * F1 + c8;
                    *(float4*)dp = r0;
                    *(float4*)(dp + 4) = r1;
                }
            }
        }
    }
}

// ---------------- Layer-2 GEMM: folds Wr projection -> 8-B record per node ---
// rec[n] = { packAB(e_src2), g = (a1@W2 row) . Wr }  (g in f32, no bf16 loss)
__global__ void gemm2_kernel(const float* __restrict__ o1, const float* __restrict__ b1,
                             const float* __restrict__ W2,
                             const float* __restrict__ a_src2, const float* __restrict__ a_dst2,
                             const float* __restrict__ Wr,
                             uint2* __restrict__ rec, float* __restrict__ ed2, int N) {
    if (blockIdx.x == 0 && threadIdx.x == 0) {
        uint2 z; z.x = 0u; z.y = 0u;
        rec[N] = z;                     // dummy node: w==0, g==0
    }
    int half = threadIdx.x >> 5;
    int n = blockIdx.x * 8 + half;
    int j = threadIdx.x & 31;
    __shared__ float a1s[8][F1];
    if (n < N) {
#pragma unroll
        for (int r = 0; r < 2; ++r) {
            int k = r * 32 + j;
            float v = o1[(size_t)n * F1 + k] + b1[k];
            a1s[half][k] = v > 0.f ? v : expm1f(v); // ELU
        }
    }
    __syncthreads();
    if (n >= N) return;
    float acc = 0.f;
#pragma unroll
    for (int k = 0; k < F1; ++k) acc = fmaf(a1s[half][k], W2[k * F2 + j], acc);
    float vs = acc * a_src2[j];
    float vd = acc * a_dst2[j];
    float vg = acc * Wr[j];
#pragma unroll
    for (int off = 16; off >= 1; off >>= 1) {
        vs += __shfl_down(vs, off, 32);
        vd += __shfl_down(vd, off, 32);
        vg += __shfl_down(vg, off, 32);
    }
    if (j == 0) {
        uint2 r; r.x = packAB(vs); r.y = __float_as_uint(vg);
        rec[n] = r;
        ed2[n] = vd;
    }
}

// ---------------- Layer-2 edge pass: scalar-projected gather -----------------
__global__ void __launch_bounds__(256, 8)
edge2_gather(const int* __restrict__ bcnt, const int* __restrict__ boff,
             const uint_t* __restrict__ pk,
             const uint2* __restrict__ rec, const float* __restrict__ ed2,
             const float* __restrict__ b2, const float* __restrict__ Wr,
             float* __restrict__ pooled, int* __restrict__ ctr, int NB, int N) {
    int tid = threadIdx.x;
    int wv = tid >> 6;
    int L = tid & 63;
    __shared__ int ldeg[BW], loff[BW], ldgp[BW], lcur[BW];
    __shared__ int lsrc[CAPL];
    __shared__ int sbk, stot;
    __shared__ float ls[4];
    float t0 = (L < F2) ? b2[L] * Wr[L] : 0.f;
    FOLD64(t0);
    float b2w = t0;          // dot(b2, Wr), identical on all lanes
    float part = 0.f;
    for (;;) {
        if (tid == 0) sbk = atomicAdd(ctr, 1);
        __syncthreads();
        int b = sbk;
        if (b >= NB) break;
        int d0 = b << SHIFT;
        int cnt = bcnt[b];
        int gbase = boff[b];
        if (cnt <= CAPL - 8 * BW - 16) {
            if (tid < BW) ldeg[tid] = 0;
            __syncthreads();
            for (int k = tid; k < cnt; k += 256) atomicAdd(&ldeg[pk[gbase + k] & (BW - 1)], 1);
            __syncthreads();
            if (tid < BW) {
                int v = ldeg[tid];
                int vp = (v + 7) & ~7;
                int e = vp;
#pragma unroll
                for (int o = 1; o < BW; o <<= 1) {
                    int u = __shfl_up(e, o, 64);
                    if (tid >= o) e += u;
                }
                e -= vp;
                loff[tid] = e;
                lcur[tid] = e;
                ldgp[tid] = vp;
                if (tid == BW - 1) stot = e + vp;
            }
            __syncthreads();
            int tot = stot;
            for (int k = tid; k < tot + 16; k += 256) lsrc[k] = N;
            __syncthreads();
            for (int k = tid; k < cnt; k += 256) {
                uint_t v = pk[gbase + k];
                int pos = atomicAdd(&lcur[v & (BW - 1)], 1);
                lsrc[pos] = (int)(v >> SHIFT);
            }
            __syncthreads();
            for (int ld = wv * 8; ld < wv * 8 + 8; ++ld) {
                int d = d0 + ld;
                if (d >= N) break;
                int st = loff[ld], en = st + ldgp[ld];
                float edv = ed2[d];
                float Ad = __expf(edv), Bd = __expf(NEG_SLOPE * edv);
                float acc = 0.f, wsm = 0.f;
                for (int k = st; k < en; k += 64) {
                    int i = k + L;
                    bool ok = i < en;
                    int s = lsrc[ok ? i : st];
                    uint2 r = rec[s];
                    float w = ok ? fmaxf(LO16(r.x) * Ad, HI16(r.x) * Bd) : 0.f;
                    acc = fmaf(w, __uint_as_float(r.y), acc);
                    wsm += w;
                }
                FOLD64(acc); FOLD64(wsm);
                part += acc / wsm + b2w;   // identical on all lanes; lane 0 used below
            }
        } else {
            for (int ld = wv * 8; ld < wv * 8 + 8; ++ld) {
                int d = d0 + ld;
                if (d >= N) break;
                float edv = ed2[d];
                float Ad = __expf(edv), Bd = __expf(NEG_SLOPE * edv);
                float acc = 0.f, wsm = 0.f;
                for (int k0 = 0; k0 < cnt; k0 += 64) {
                    int i = k0 + L;
                    bool ok = i < cnt;
                    uint_t v = pk[gbase + (ok ? i : 0)];
                    int s = (int)(v >> SHIFT);
                    bool mm = ok && ((int)(v & (BW - 1)) == ld);
                    uint2 r = rec[s];
                    float w = mm ? fmaxf(LO16(r.x) * Ad, HI16(r.x) * Bd) : 0.f;
                    acc = fmaf(w, __uint_as_float(r.y), acc);
                    wsm += w;
                }
                FOLD64(acc); FOLD64(wsm);
                part += acc / wsm + b2w;
            }
        }
    }
    if (L == 0) ls[wv] = part;
    __syncthreads();
    if (tid == 0) atomicAdd(pooled, ls[0] + ls[1] + ls[2] + ls[3]);
}

__global__ void final_kernel(const float* __restrict__ pooled, const float* __restrict__ br,
                             float* __restrict__ out) {
    if (threadIdx.x == 0 && blockIdx.x == 0) out[0] = pooled[0] + br[0];
}

static inline size_t al128(size_t v) { return (v + 127) & ~(size_t)127; }

extern "C" void kernel_launch(void* const* d_in, const int* in_sizes, int n_in,
                              void* d_out, int out_size, void* d_ws, size_t ws_size,
                              hipStream_t stream) {
    const float* x    = (const float*)d_in[0];
    const int*   ei   = (const int*)d_in[1];
    const float* W1   = (const float*)d_in[2];
    const float* a_s1 = (const float*)d_in[3];
    const float* a_d1 = (const float*)d_in[4];
    const float* b1   = (const float*)d_in[5];
    const float* W2   = (const float*)d_in[6];
    const float* a_s2 = (const float*)d_in[7];
    const float* a_d2 = (const float*)d_in[8];
    const float* b2   = (const float*)d_in[9];
    const float* Wr   = (const float*)d_in[10];
    const float* br   = (const float*)d_in[11];
    float* out = (float*)d_out;

    int N = in_sizes[0] / FIN;
    int E = in_sizes[1] / 2;
    size_t n = (size_t)N;
    int NB = (N + BW - 1) >> SHIFT;
    int NSB = (N + ((1 << SB_SHIFT) - 1)) >> SB_SHIFT;

    // workspace layout (bytes); all hot arrays 128-B aligned.
    // CRITICAL: h1 rows are 128 B and gathered randomly -- h1 base MUST be
    // 128-aligned or every row straddles two cache lines (R4: FETCH +64%).
    char* ws = (char*)d_ws;
    size_t off_o1  = 0;                                   // 256N
    size_t off_sp1 = al128(off_o1 + n * 256);             // 32N + 32 (dummy row)
    size_t off_ed1 = al128(off_sp1 + n * 32 + 32);        // 32N
    size_t off_h1  = al128(off_ed1 + n * 32);             // 128N + 128 (dummy row)
    size_t off_pk  = al128(off_h1 + n * 128 + 128);
    float*    o1   = (float*)(ws + off_o1);
    uint_t*   sp1  = (uint_t*)(ws + off_sp1);
    float*    ed1  = (float*)(ws + off_ed1);
    ushort_t* h1   = (ushort_t*)(ws + off_h1);
    uint_t*   pk   = (uint_t*)(ws + off_pk);
    size_t pk_static = (size_t)NB * CAP_G * 4;            // ~17.6 MB
    size_t pk_exact  = (size_t)(E + N) * 4;               // ~13.2 MB
    // sbdata overlays o1 (disjoint lifetimes)
    uint_t* sbdata = (uint_t*)ws;
    bool use_static = (NSB <= NSBMAX) &&
                      ((size_t)NSB * SBCAP * 4 <= n * 256) &&
                      (ws_size >= off_pk + pk_static + (size_t)NBMAX * 16 +
                                  (size_t)NSBMAX * 4 + 128);
    char* tail = ws + off_pk + (use_static ? pk_static : pk_exact);
    int*      bcnt  = (int*)tail;                         // NBMAX int
    int*      boff  = (int*)(tail + NBMAX * 4);           // NBMAX int
    int*      bcur  = (int*)(tail + NBMAX * 8);           // NBMAX int
    int*      sbcnt = (int*)(tail + NBMAX * 12);          // NSBMAX int
    float*  pooled  = (float*)(tail + NBMAX * 12 + NSBMAX * 4); // 1 f32
    int*      ctrs  = (int*)(tail + NBMAX * 12 + NSBMAX * 4 + 8); // 2 int
    // layer-2 overlays (dead after edge1): rec over h1, ed2 over ed1
    uint2* rec = (uint2*)h1;
    float* ed2 = ed1;

    int egrid = NB < 2048 ? NB : 2048;

    zerob_kernel<<<8, 256, 0, stream>>>(bcnt, boff, NB, pooled,
                                        use_static ? CAP_G : 0, sbcnt, NSB,
                                        sp1, h1, ctrs, N);
    if (use_static) {
        int EN = E + N;
        int G1 = (EN + P_CHUNK - 1) / P_CHUNK;
        part1_kernel<<<G1, 256, 0, stream>>>(ei, E, N, sbcnt, sbdata);
        part2_kernel<<<NSB * BPS, 256, 0, stream>>>(sbdata, sbcnt, bcnt, boff, pk);
        gemm1_kernel<<<(N + 15) / 16, 256, 0, stream>>>(x, W1, a_s1, a_d1, h1, sp1, ed1, N);
    } else {
        gemm1_kernel<<<(N + 15) / 16, 256, 0, stream>>>(x, W1, a_s1, a_d1, h1, sp1, ed1, N);
        bhist_kernel<<<256, 256, 0, stream>>>(ei, E, N, bcnt, NB);
        bscan_kernel<<<1, 64, 0, stream>>>(bcnt, NB, boff, bcur);
        bscat_kernel<<<256, 256, 0, stream>>>(ei, E, N, bcur, pk, NB);
    }
    edge1_gather<<<egrid, 256, 0, stream>>>(bcnt, boff, pk, sp1, ed1, h1, o1,
                                            ctrs + 0, NB, N);
    gemm2_kernel<<<(N + 7) / 8, 256, 0, stream>>>(o1, b1, W2, a_s2, a_d2, Wr, rec, ed2, N);
    edge2_gather<<<egrid, 256, 0, stream>>>(bcnt, boff, pk, rec, ed2, b2, Wr, pooled,
                                            ctrs + 1, NB, N);
    final_kernel<<<1, 64, 0, stream>>>(pooled, br, out);
}

// Round 7
// 454.577 us; speedup vs baseline: 1.0971x; 1.0091x over previous
//
#include <hip/hip_runtime.h>
#include <math.h>

#define NEG_SLOPE 0.2f
#define FIN 128
#define H1 8
#define F1 64   // HEADS1*HID
#define F2 32   // OUT2

#define SHIFT 5
#define BW 32          // dsts per bucket
#define CAPL 2048      // LDS edge slots per bucket (mean ~1056, sigma ~32)
#define CAP_G 1408     // static pk slots per bucket (mean+11sigma)
#define NBMAX 4096

// two-pass radix partition (write-coalescing fix for the 7x write amplification)
#define SB_SHIFT 11            // 2048 nodes per super-bucket = 64 final buckets
#define NSBMAX 64              // supports N <= 131072
#define P_CHUNK 2048           // edges per partition block
#define BPS 35                 // pass-2 blocks per SB
#define SBCAP (BPS * P_CHUNK)  // slots per SB in sbdata

typedef unsigned short ushort_t;
typedef unsigned int uint_t;

#define LO16(u) __uint_as_float((u) << 16)
#define HI16(u) __uint_as_float((u) & 0xffff0000u)

// fold across the 4 edge slots (lane bits 4..5) -- R3-proven edge1 shape
#define FOLDQ4(x) { x += __shfl_xor(x, 16, 64); x += __shfl_xor(x, 32, 64); }
// fold across all 64 lanes
#define FOLD64(x) { x += __shfl_xor(x, 1, 64); x += __shfl_xor(x, 2, 64); x += __shfl_xor(x, 4, 64); \
                    x += __shfl_xor(x, 8, 64); x += __shfl_xor(x, 16, 64); x += __shfl_xor(x, 32, 64); }

static __device__ __forceinline__ ushort_t f2bf(float f) {
    uint_t u = __float_as_uint(f);
    u = (u + 0x7FFFu + ((u >> 16) & 1u)) >> 16; // RNE
    return (ushort_t)u;
}
// pack {A=exp(e), B=exp(0.2e)} as bf16x2: A in low 16, B in high 16
static __device__ __forceinline__ uint_t packAB(float e) {
    return (uint_t)f2bf(__expf(e)) | ((uint_t)f2bf(__expf(NEG_SLOPE * e)) << 16);
}

// ---------------- Layer-1 GEMM: h1 = x @ W1 (bf16 out), fused exp-tables -----
__global__ void gemm1_kernel(const float* __restrict__ x, const float* __restrict__ W1,
                             const float* __restrict__ a_src, const float* __restrict__ a_dst,
                             ushort_t* __restrict__ h1, uint_t* __restrict__ sp,
                             float* __restrict__ ed, int N) {
    __shared__ float xs[16][FIN]; // 8 KB
    int tid = threadIdx.x;
    int n0 = blockIdx.x * 16;
    for (int i = tid; i < 16 * FIN; i += 256) {
        int nn = n0 + (i >> 7);
        xs[i >> 7][i & 127] = (nn < N) ? x[(size_t)nn * FIN + (i & 127)] : 0.f;
    }
    __syncthreads();
    int wv = tid >> 6, j = tid & 63;
    int nb = wv << 2;
    float a0 = 0.f, a1 = 0.f, a2 = 0.f, a3 = 0.f;
#pragma unroll 2
    for (int k = 0; k < FIN; k += 4) {
        float w0 = W1[(k + 0) * F1 + j];
        float w1 = W1[(k + 1) * F1 + j];
        float w2 = W1[(k + 2) * F1 + j];
        float w3 = W1[(k + 3) * F1 + j];
        float4 x0 = *(const float4*)&xs[nb + 0][k];
        float4 x1 = *(const float4*)&xs[nb + 1][k];
        float4 x2 = *(const float4*)&xs[nb + 2][k];
        float4 x3 = *(const float4*)&xs[nb + 3][k];
        a0 = fmaf(x0.x, w0, fmaf(x0.y, w1, fmaf(x0.z, w2, fmaf(x0.w, w3, a0))));
        a1 = fmaf(x1.x, w0, fmaf(x1.y, w1, fmaf(x1.z, w2, fmaf(x1.w, w3, a1))));
        a2 = fmaf(x2.x, w0, fmaf(x2.y, w1, fmaf(x2.z, w2, fmaf(x2.w, w3, a2))));
        a3 = fmaf(x3.x, w0, fmaf(x3.y, w1, fmaf(x3.z, w2, fmaf(x3.w, w3, a3))));
    }
    float as = a_src[j], ad = a_dst[j];
    float av[4] = {a0, a1, a2, a3};
#pragma unroll
    for (int t = 0; t < 4; ++t) {
        int n = n0 + nb + t;
        if (n >= N) break;
        h1[(size_t)n * F1 + j] = f2bf(av[t]);
        float vs = av[t] * as;
        float vd = av[t] * ad;
#pragma unroll
        for (int off = 4; off >= 1; off >>= 1) {
            vs += __shfl_down(vs, off, 8);
            vd += __shfl_down(vd, off, 8);
        }
        if ((j & 7) == 0) {
            sp[n * H1 + (j >> 3)] = packAB(vs);
            ed[n * H1 + (j >> 3)] = vd;
        }
    }
}

// ---------------- init: counters, dummy node (padding target for edge2) ------
__global__ void zerob_kernel(int* __restrict__ bcnt, int* __restrict__ boff,
                             int NB, float* __restrict__ pooled, int capg,
                             int* __restrict__ sbcnt, int nsb,
                             uint_t* __restrict__ sp1, ushort_t* __restrict__ h1,
                             int* __restrict__ ctrs, int N) {
    int t = blockIdx.x * blockDim.x + threadIdx.x;
    int stride = gridDim.x * blockDim.x;
    for (int i = t; i < NB; i += stride) {
        bcnt[i] = 0;
        if (capg) boff[i] = i * capg;
    }
    for (int i = t; i < nsb; i += stride) sbcnt[i] = 0;
    if (t < H1) sp1[(size_t)N * H1 + t] = 0u;              // dummy: weight == 0
    if (t >= 8 && t < 8 + F1) h1[(size_t)N * F1 + (t - 8)] = 0; // dummy: finite row
    if (t == 72) pooled[0] = 0.f;
    if (t == 73) ctrs[0] = 0;
    if (t == 74) ctrs[1] = 0;
}

// ---------------- Pass 1: partition edges into super-buckets (coalesced) -----
__global__ void __launch_bounds__(256, 4)
part1_kernel(const int* __restrict__ ei, int E, int N,
             int* __restrict__ sbcnt, uint_t* __restrict__ sbdata) {
    __shared__ int hist[NSBMAX];
    __shared__ int loff[NSBMAX];
    __shared__ int lcur[NSBMAX];
    __shared__ int gb[NSBMAX];
    __shared__ uint_t buf[P_CHUNK];
    __shared__ unsigned char sbarr[P_CHUNK];
    int tid = threadIdx.x;
    int NSB = (N + ((1 << SB_SHIFT) - 1)) >> SB_SHIFT;
    for (int i = tid; i < NSB; i += 256) hist[i] = 0;
    __syncthreads();
    int EN = E + N;
    int base = blockIdx.x * P_CHUNK;
    int m = EN - base; if (m > P_CHUNK) m = P_CHUNK;
    int t0 = base + tid * 8;
    int s[8], d[8];
    bool fast = (t0 + 8 <= E) && ((E & 3) == 0);
    if (fast) {
        int4 a = *(const int4*)&ei[t0];
        int4 b = *(const int4*)&ei[t0 + 4];
        s[0]=a.x; s[1]=a.y; s[2]=a.z; s[3]=a.w; s[4]=b.x; s[5]=b.y; s[6]=b.z; s[7]=b.w;
        int4 c = *(const int4*)&ei[E + t0];
        int4 e2 = *(const int4*)&ei[E + t0 + 4];
        d[0]=c.x; d[1]=c.y; d[2]=c.z; d[3]=c.w; d[4]=e2.x; d[5]=e2.y; d[6]=e2.z; d[7]=e2.w;
    } else {
#pragma unroll
        for (int r = 0; r < 8; ++r) {
            int t = t0 + r;
            if (t < EN) {
                if (t < E) { s[r] = ei[t]; d[r] = ei[E + t]; }
                else       { s[r] = d[r] = t - E; }
            } else d[r] = -1;
        }
    }
#pragma unroll
    for (int r = 0; r < 8; ++r)
        if (d[r] >= 0) atomicAdd(&hist[d[r] >> SB_SHIFT], 1);
    __syncthreads();
    if (tid < 64) {
        int v = (tid < NSB) ? hist[tid] : 0;
        int e = v;
#pragma unroll
        for (int o = 1; o < 64; o <<= 1) {
            int u = __shfl_up(e, o, 64);
            if (tid >= o) e += u;
        }
        e -= v; // exclusive prefix
        if (tid < NSB) {
            loff[tid] = e;
            lcur[tid] = e;
            gb[tid] = v ? atomicAdd(&sbcnt[tid], v) : 0;
        }
    }
    __syncthreads();
#pragma unroll
    for (int r = 0; r < 8; ++r)
        if (d[r] >= 0) {
            int sb = d[r] >> SB_SHIFT;
            int pos = atomicAdd(&lcur[sb], 1);
            buf[pos] = ((uint_t)s[r] << SB_SHIFT) | (uint_t)(d[r] & ((1 << SB_SHIFT) - 1));
            sbarr[pos] = (unsigned char)sb;
        }
    __syncthreads();
    for (int i = tid; i < m; i += 256) {
        int sb = sbarr[i];
        int idx = gb[sb] + (i - loff[sb]);
        if (idx < SBCAP)
            sbdata[(size_t)sb * SBCAP + idx] = buf[i];
    }
}

// ---------------- Pass 2: scatter within SB to final pk buckets (coalesced) --
__global__ void __launch_bounds__(256, 4)
part2_kernel(const uint_t* __restrict__ sbdata, const int* __restrict__ sbcnt,
             int* __restrict__ bcnt, const int* __restrict__ boff,
             uint_t* __restrict__ pk) {
    __shared__ int hist[64];
    __shared__ int loff[64];
    __shared__ int lcur[64];
    __shared__ int gb[64];
    __shared__ uint_t buf[P_CHUNK];
    int tid = threadIdx.x;
    int sb = blockIdx.x / BPS;
    int base = (blockIdx.x % BPS) * P_CHUNK;
    int cnt = sbcnt[sb];
    if (cnt > SBCAP) cnt = SBCAP;
    if (base >= cnt) return;
    int m = cnt - base; if (m > P_CHUNK) m = P_CHUNK;
    if (tid < 64) hist[tid] = 0;
    __syncthreads();
    const uint_t* src = sbdata + (size_t)sb * SBCAP + base;
    uint_t v[8];
#pragma unroll
    for (int r = 0; r < 8; ++r) {
        int i = tid + r * 256; // coalesced strided read
        if (i < m) {
            v[r] = src[i];
            atomicAdd(&hist[(v[r] >> 5) & 63], 1);
        }
    }
    __syncthreads();
    if (tid < 64) {
        int c = hist[tid];
        int e = c;
#pragma unroll
        for (int o = 1; o < 64; o <<= 1) {
            int u = __shfl_up(e, o, 64);
            if (tid >= o) e += u;
        }
        e -= c;
        loff[tid] = e;
        lcur[tid] = e;
        int bucket = (sb << 6) + tid;
        gb[tid] = c ? (boff[bucket] + atomicAdd(&bcnt[bucket], c)) : 0;
    }
    __syncthreads();
#pragma unroll
    for (int r = 0; r < 8; ++r) {
        int i = tid + r * 256;
        if (i < m) {
            int lb = (v[r] >> 5) & 63;
            int pos = atomicAdd(&lcur[lb], 1);
            buf[pos] = v[r];
        }
    }
    __syncthreads();
    for (int i = tid; i < m; i += 256) {
        uint_t u = buf[i];
        int lb = (u >> 5) & 63;
        int idx = gb[lb] + (i - loff[lb]);
        pk[idx] = ((u >> SB_SHIFT) << SHIFT) | (u & (BW - 1));
    }
}

// ---- exact-CSR fallback path (used only when ws_size too small for static) --
__global__ void bhist_kernel(const int* __restrict__ ei, int E, int N,
                             int* __restrict__ bcnt, int NB) {
    __shared__ int h[NBMAX];
    int tid = threadIdx.x;
    for (int i = tid; i < NB; i += 256) h[i] = 0;
    __syncthreads();
    int EN = E + N;
    int chunk = (EN + gridDim.x - 1) / gridDim.x;
    int e0 = blockIdx.x * chunk;
    int e1 = e0 + chunk; if (e1 > EN) e1 = EN;
    for (int t = e0 + tid; t < e1; t += 256) {
        int d = (t < E) ? ei[E + t] : (t - E);
        atomicAdd(&h[d >> SHIFT], 1);
    }
    __syncthreads();
    for (int i = tid; i < NB; i += 256)
        if (h[i]) atomicAdd(&bcnt[i], h[i]);
}

__global__ void bscan_kernel(const int* __restrict__ bcnt, int NB,
                             int* __restrict__ boff, int* __restrict__ bcur) {
    int lane = threadIdx.x; // 0..63
    int chunk = (NB + 63) >> 6;
    int lo = lane * chunk;
    int hi = lo + chunk; if (hi > NB) hi = NB;
    int sum = 0;
    for (int i = lo; i < hi; ++i) sum += bcnt[i];
    int e = sum;
#pragma unroll
    for (int o = 1; o < 64; o <<= 1) {
        int v = __shfl_up(e, o, 64);
        if (lane >= o) e += v;
    }
    e -= sum;
    int run = e;
    for (int i = lo; i < hi; ++i) {
        int c = bcnt[i];
        boff[i] = run;
        bcur[i] = run;
        run += c;
    }
}

__global__ void bscat_kernel(const int* __restrict__ ei, int E, int N,
                             int* __restrict__ bcur, uint_t* __restrict__ pk, int NB) {
    __shared__ int lh[NBMAX];
    __shared__ int lc[NBMAX];
    int tid = threadIdx.x;
    for (int i = tid; i < NB; i += 256) lh[i] = 0;
    __syncthreads();
    int EN = E + N;
    int chunk = (EN + gridDim.x - 1) / gridDim.x;
    int e0 = blockIdx.x * chunk;
    int e1 = e0 + chunk; if (e1 > EN) e1 = EN;
    for (int t = e0 + tid; t < e1; t += 256) {
        int d = (t < E) ? ei[E + t] : (t - E);
        atomicAdd(&lh[d >> SHIFT], 1);
    }
    __syncthreads();
    for (int i = tid; i < NB; i += 256) {
        int c = lh[i];
        lc[i] = c ? atomicAdd(&bcur[i], c) : 0;
    }
    __syncthreads();
    for (int t = e0 + tid; t < e1; t += 256) {
        int s, d;
        if (t < E) { s = ei[t]; d = ei[E + t]; } else { s = d = t - E; }
        int pos = atomicAdd(&lc[d >> SHIFT], 1);
        pk[pos] = ((uint_t)s << SHIFT) | (uint_t)(d & (BW - 1));
    }
}

// ---------------- Layer-1 edge pass: R3-proven body + persistent blocks ------
// Lane L: edge slot q=L>>4 (4 slots), channels c4=(L&15)*4 (uint2 of 4 bf16),
// head hL=(L&15)>>1. 8 edges/iter (2 groups), depth-1 prefetch, cndmask guards.
// R6 lesson: do NOT slim this loop -- its VALU work is the latency cover.
__global__ void __launch_bounds__(256, 8)
edge1_gather(const int* __restrict__ bcnt, const int* __restrict__ boff,
             const uint_t* __restrict__ pk,
             const uint_t* __restrict__ sp, const float* __restrict__ ed,
             const ushort_t* __restrict__ h1, float* __restrict__ o1,
             int* __restrict__ ctr, int NB, int N) {
    int tid = threadIdx.x;
    int wv = tid >> 6;
    int L = tid & 63;
    int q = L >> 4;           // edge slot 0..3
    int c4 = (L & 15) << 2;   // channel base
    int hL = (L & 15) >> 1;   // head of channels c4..c4+3
    __shared__ int ldeg[BW], loff[BW], lcur[BW];
    __shared__ int lsrc[CAPL];
    __shared__ int sbk;
    for (;;) {
        if (tid == 0) sbk = atomicAdd(ctr, 1);
        __syncthreads();
        int b = sbk;
        if (b >= NB) break;
        int d0 = b << SHIFT;
        int cnt = bcnt[b];
        int gbase = boff[b];
        if (cnt <= CAPL) {
            if (tid < BW) ldeg[tid] = 0;
            __syncthreads();
            for (int k = tid; k < cnt; k += 256) atomicAdd(&ldeg[pk[gbase + k] & (BW - 1)], 1);
            __syncthreads();
            if (tid < BW) {
                int v = ldeg[tid];
                int e = v;
#pragma unroll
                for (int o = 1; o < BW; o <<= 1) {
                    int u = __shfl_up(e, o, 64);
                    if (tid >= o) e += u;
                }
                e -= v;
                loff[tid] = e;
                lcur[tid] = e;
            }
            __syncthreads();
            for (int k = tid; k < cnt; k += 256) {
                uint_t v = pk[gbase + k];
                int pos = atomicAdd(&lcur[v & (BW - 1)], 1);
                lsrc[pos] = (int)(v >> SHIFT);
            }
            __syncthreads();
            for (int ld = wv * 8; ld < wv * 8 + 8; ++ld) {
                int d = d0 + ld;
                if (d >= N) break;
                int st = loff[ld], en = st + ldeg[ld];
                float edv = ed[d * H1 + hL];
                float Ad = __expf(edv), Bd = __expf(NEG_SLOPE * edv);
                float ax = 0.f, ay = 0.f, az = 0.f, aw = 0.f, wsum = 0.f;
                uint_t U0, U1; uint2 V0, V1;
                {
                    int i0 = st + q, i1 = st + 4 + q;
                    bool ok0 = i0 < en, ok1 = i1 < en;
                    int s0 = lsrc[ok0 ? i0 : st];   // st valid: self-loop => en>st
                    int s1 = lsrc[ok1 ? i1 : st];
                    uint_t u0 = sp[s0 * H1 + hL];
                    uint_t u1 = sp[s1 * H1 + hL];
                    V0 = *(const uint2*)(h1 + ((size_t)s0 << 6) + c4);
                    V1 = *(const uint2*)(h1 + ((size_t)s1 << 6) + c4);
                    U0 = ok0 ? u0 : 0u;
                    U1 = ok1 ? u1 : 0u;
                }
                for (int k = st; k < en; k += 8) {
                    uint_t N0, N1; uint2 P0, P1;
                    {
                        int i0 = k + 8 + q, i1 = k + 12 + q;
                        bool ok0 = i0 < en, ok1 = i1 < en;
                        int s0 = lsrc[ok0 ? i0 : st];
                        int s1 = lsrc[ok1 ? i1 : st];
                        uint_t u0 = sp[s0 * H1 + hL];
                        uint_t u1 = sp[s1 * H1 + hL];
                        P0 = *(const uint2*)(h1 + ((size_t)s0 << 6) + c4);
                        P1 = *(const uint2*)(h1 + ((size_t)s1 << 6) + c4);
                        N0 = ok0 ? u0 : 0u;
                        N1 = ok1 ? u1 : 0u;
                    }
                    float w0 = fmaxf(LO16(U0) * Ad, HI16(U0) * Bd);
                    float w1 = fmaxf(LO16(U1) * Ad, HI16(U1) * Bd);
                    ax = fmaf(w0, LO16(V0.x), ax);
                    ay = fmaf(w0, HI16(V0.x), ay);
                    az = fmaf(w0, LO16(V0.y), az);
                    aw = fmaf(w0, HI16(V0.y), aw);
                    ax = fmaf(w1, LO16(V1.x), ax);
                    ay = fmaf(w1, HI16(V1.x), ay);
                    az = fmaf(w1, LO16(V1.y), az);
                    aw = fmaf(w1, HI16(V1.y), aw);
                    wsum += w0 + w1;
                    U0 = N0; U1 = N1; V0 = P0; V1 = P1;
                }
                FOLDQ4(ax); FOLDQ4(ay); FOLDQ4(az); FOLDQ4(aw); FOLDQ4(wsum);
                if (q == 0) {
                    float inv = 1.f / wsum;
                    float4 r; r.x = ax * inv; r.y = ay * inv; r.z = az * inv; r.w = aw * inv;
                    *(float4*)(o1 + (size_t)d * F1 + c4) = r;
                }
            }
        } else {
            // statistically unreachable fallback: masked whole-bucket scan
            for (int ld = wv * 8; ld < wv * 8 + 8; ++ld) {
                int d = d0 + ld;
                if (d >= N) break;
                float edv = ed[d * H1 + hL];
                float Ad = __expf(edv), Bd = __expf(NEG_SLOPE * edv);
                float ax = 0.f, ay = 0.f, az = 0.f, aw = 0.f, wsum = 0.f;
                for (int k0 = 0; k0 < cnt; k0 += 4) {
                    int idx = k0 + q;
                    bool ok = idx < cnt;
                    uint_t v = pk[gbase + (ok ? idx : 0)];
                    int s = (int)(v >> SHIFT);
                    bool m = ok && ((int)(v & (BW - 1)) == ld);
                    uint_t u = sp[(uint_t)s * H1 + hL];
                    float w = m ? fmaxf(LO16(u) * Ad, HI16(u) * Bd) : 0.f;
                    uint2 hv = *(const uint2*)(h1 + ((size_t)s << 6) + c4);
                    ax = fmaf(w, LO16(hv.x), ax);
                    ay = fmaf(w, HI16(hv.x), ay);
                    az = fmaf(w, LO16(hv.y), az);
                    aw = fmaf(w, HI16(hv.y), aw);
                    wsum += w;
                }
                FOLDQ4(ax); FOLDQ4(ay); FOLDQ4(az); FOLDQ4(aw); FOLDQ4(wsum);
                if (q == 0) {
                    float inv = 1.f / wsum;
                    float4 r; r.x = ax * inv; r.y = ay * inv; r.z = az * inv; r.w = aw * inv;
                    *(float4*)(o1 + (size_t)d * F1 + c4) = r;
                }
            }
        }
    }
}

// ---------------- Layer-2 GEMM: folds Wr projection -> 8-B record per node ---
// rec[n] = { packAB(e_src2), g = (a1@W2 row) . Wr }  (g in f32, no bf16 loss)
__global__ void gemm2_kernel(const float* __restrict__ o1, const float* __restrict__ b1,
                             const float* __restrict__ W2,
                             const float* __restrict__ a_src2, const float* __restrict__ a_dst2,
                             const float* __restrict__ Wr,
                             uint2* __restrict__ rec, float* __restrict__ ed2, int N) {
    if (blockIdx.x == 0 && threadIdx.x == 0) {
        uint2 z; z.x = 0u; z.y = 0u;
        rec[N] = z;                     // dummy node: w==0, g==0
    }
    int half = threadIdx.x >> 5;
    int n = blockIdx.x * 8 + half;
    int j = threadIdx.x & 31;
    __shared__ float a1s[8][F1];
    if (n < N) {
#pragma unroll
        for (int r = 0; r < 2; ++r) {
            int k = r * 32 + j;
            float v = o1[(size_t)n * F1 + k] + b1[k];
            a1s[half][k] = v > 0.f ? v : expm1f(v); // ELU
        }
    }
    __syncthreads();
    if (n >= N) return;
    float acc = 0.f;
#pragma unroll
    for (int k = 0; k < F1; ++k) acc = fmaf(a1s[half][k], W2[k * F2 + j], acc);
    float vs = acc * a_src2[j];
    float vd = acc * a_dst2[j];
    float vg = acc * Wr[j];
#pragma unroll
    for (int off = 16; off >= 1; off >>= 1) {
        vs += __shfl_down(vs, off, 32);
        vd += __shfl_down(vd, off, 32);
        vg += __shfl_down(vg, off, 32);
    }
    if (j == 0) {
        uint2 r; r.x = packAB(vs); r.y = __float_as_uint(vg);
        rec[n] = r;
        ed2[n] = vd;
    }
}

// ---------------- Layer-2 edge pass: scalar-projected gather -----------------
__global__ void __launch_bounds__(256, 8)
edge2_gather(const int* __restrict__ bcnt, const int* __restrict__ boff,
             const uint_t* __restrict__ pk,
             const uint2* __restrict__ rec, const float* __restrict__ ed2,
             const float* __restrict__ b2, const float* __restrict__ Wr,
             float* __restrict__ pooled, int* __restrict__ ctr, int NB, int N) {
    int tid = threadIdx.x;
    int wv = tid >> 6;
    int L = tid & 63;
    __shared__ int ldeg[BW], loff[BW], ldgp[BW], lcur[BW];
    __shared__ int lsrc[CAPL];
    __shared__ int sbk, stot;
    __shared__ float ls[4];
    float t0 = (L < F2) ? b2[L] * Wr[L] : 0.f;
    FOLD64(t0);
    float b2w = t0;          // dot(b2, Wr), identical on all lanes
    float part = 0.f;
    for (;;) {
        if (tid == 0) sbk = atomicAdd(ctr, 1);
        __syncthreads();
        int b = sbk;
        if (b >= NB) break;
        int d0 = b << SHIFT;
        int cnt = bcnt[b];
        int gbase = boff[b];
        if (cnt <= CAPL - 8 * BW - 16) {
            if (tid < BW) ldeg[tid] = 0;
            __syncthreads();
            for (int k = tid; k < cnt; k += 256) atomicAdd(&ldeg[pk[gbase + k] & (BW - 1)], 1);
            __syncthreads();
            if (tid < BW) {
                int v = ldeg[tid];
                int vp = (v + 7) & ~7;
                int e = vp;
#pragma unroll
                for (int o = 1; o < BW; o <<= 1) {
                    int u = __shfl_up(e, o, 64);
                    if (tid >= o) e += u;
                }
                e -= vp;
                loff[tid] = e;
                lcur[tid] = e;
                ldgp[tid] = vp;
                if (tid == BW - 1) stot = e + vp;
            }
            __syncthreads();
            int tot = stot;
            for (int k = tid; k < tot + 16; k += 256) lsrc[k] = N;
            __syncthreads();
            for (int k = tid; k < cnt; k += 256) {
                uint_t v = pk[gbase + k];
                int pos = atomicAdd(&lcur[v & (BW - 1)], 1);
                lsrc[pos] = (int)(v >> SHIFT);
            }
            __syncthreads();
            for (int ld = wv * 8; ld < wv * 8 + 8; ++ld) {
                int d = d0 + ld;
                if (d >= N) break;
                int st = loff[ld], en = st + ldgp[ld];
                float edv = ed2[d];
                float Ad = __expf(edv), Bd = __expf(NEG_SLOPE * edv);
                float acc = 0.f, wsm = 0.f;
                for (int k = st; k < en; k += 64) {
                    int i = k + L;
                    bool ok = i < en;
                    int s = lsrc[ok ? i : st];
                    uint2 r = rec[s];
                    float w = ok ? fmaxf(LO16(r.x) * Ad, HI16(r.x) * Bd) : 0.f;
                    acc = fmaf(w, __uint_as_float(r.y), acc);
                    wsm += w;
                }
                FOLD64(acc); FOLD64(wsm);
                part += acc / wsm + b2w;   // identical on all lanes; lane 0 used below
            }
        } else {
            for (int ld = wv * 8; ld < wv * 8 + 8; ++ld) {
                int d = d0 + ld;
                if (d >= N) break;
                float edv = ed2[d];
                float Ad = __expf(edv), Bd = __expf(NEG_SLOPE * edv);
                float acc = 0.f, wsm = 0.f;
                for (int k0 = 0; k0 < cnt; k0 += 64) {
                    int i = k0 + L;
                    bool ok = i < cnt;
                    uint_t v = pk[gbase + (ok ? i : 0)];
                    int s = (int)(v >> SHIFT);
                    bool mm = ok && ((int)(v & (BW - 1)) == ld);
                    uint2 r = rec[s];
                    float w = mm ? fmaxf(LO16(r.x) * Ad, HI16(r.x) * Bd) : 0.f;
                    acc = fmaf(w, __uint_as_float(r.y), acc);
                    wsm += w;
                }
                FOLD64(acc); FOLD64(wsm);
                part += acc / wsm + b2w;
            }
        }
    }
    if (L == 0) ls[wv] = part;
    __syncthreads();
    if (tid == 0) atomicAdd(pooled, ls[0] + ls[1] + ls[2] + ls[3]);
}

__global__ void final_kernel(const float* __restrict__ pooled, const float* __restrict__ br,
                             float* __restrict__ out) {
    if (threadIdx.x == 0 && blockIdx.x == 0) out[0] = pooled[0] + br[0];
}

static inline size_t al128(size_t v) { return (v + 127) & ~(size_t)127; }

extern "C" void kernel_launch(void* const* d_in, const int* in_sizes, int n_in,
                              void* d_out, int out_size, void* d_ws, size_t ws_size,
                              hipStream_t stream) {
    const float* x    = (const float*)d_in[0];
    const int*   ei   = (const int*)d_in[1];
    const float* W1   = (const float*)d_in[2];
    const float* a_s1 = (const float*)d_in[3];
    const float* a_d1 = (const float*)d_in[4];
    const float* b1   = (const float*)d_in[5];
    const float* W2   = (const float*)d_in[6];
    const float* a_s2 = (const float*)d_in[7];
    const float* a_d2 = (const float*)d_in[8];
    const float* b2   = (const float*)d_in[9];
    const float* Wr   = (const float*)d_in[10];
    const float* br   = (const float*)d_in[11];
    float* out = (float*)d_out;

    int N = in_sizes[0] / FIN;
    int E = in_sizes[1] / 2;
    size_t n = (size_t)N;
    int NB = (N + BW - 1) >> SHIFT;
    int NSB = (N + ((1 << SB_SHIFT) - 1)) >> SB_SHIFT;

    // workspace layout (bytes); all hot arrays 128-B aligned.
    // CRITICAL: h1 rows are 128 B and gathered randomly -- h1 base MUST be
    // 128-aligned or every row straddles two cache lines (R4: FETCH +64%).
    char* ws = (char*)d_ws;
    size_t off_o1  = 0;                                   // 256N
    size_t off_sp1 = al128(off_o1 + n * 256);             // 32N + 32 (dummy row)
    size_t off_ed1 = al128(off_sp1 + n * 32 + 32);        // 32N
    size_t off_h1  = al128(off_ed1 + n * 32);             // 128N + 128 (dummy row)
    size_t off_pk  = al128(off_h1 + n * 128 + 128);
    float*    o1   = (float*)(ws + off_o1);
    uint_t*   sp1  = (uint_t*)(ws + off_sp1);
    float*    ed1  = (float*)(ws + off_ed1);
    ushort_t* h1   = (ushort_t*)(ws + off_h1);
    uint_t*   pk   = (uint_t*)(ws + off_pk);
    size_t pk_static = (size_t)NB * CAP_G * 4;            // ~17.6 MB
    size_t pk_exact  = (size_t)(E + N) * 4;               // ~13.2 MB
    // sbdata overlays o1 (disjoint lifetimes)
    uint_t* sbdata = (uint_t*)ws;
    bool use_static = (NSB <= NSBMAX) &&
                      ((size_t)NSB * SBCAP * 4 <= n * 256) &&
                      (ws_size >= off_pk + pk_static + (size_t)NBMAX * 16 +
                                  (size_t)NSBMAX * 4 + 128);
    char* tail = ws + off_pk + (use_static ? pk_static : pk_exact);
    int*      bcnt  = (int*)tail;                         // NBMAX int
    int*      boff  = (int*)(tail + NBMAX * 4);           // NBMAX int
    int*      bcur  = (int*)(tail + NBMAX * 8);           // NBMAX int
    int*      sbcnt = (int*)(tail + NBMAX * 12);          // NSBMAX int
    float*  pooled  = (float*)(tail + NBMAX * 12 + NSBMAX * 4); // 1 f32
    int*      ctrs  = (int*)(tail + NBMAX * 12 + NSBMAX * 4 + 8); // 2 int
    // layer-2 overlays (dead after edge1): rec over h1, ed2 over ed1
    uint2* rec = (uint2*)h1;
    float* ed2 = ed1;

    int egrid = NB < 2048 ? NB : 2048;

    zerob_kernel<<<8, 256, 0, stream>>>(bcnt, boff, NB, pooled,
                                        use_static ? CAP_G : 0, sbcnt, NSB,
                                        sp1, h1, ctrs, N);
    if (use_static) {
        int EN = E + N;
        int G1 = (EN + P_CHUNK - 1) / P_CHUNK;
        part1_kernel<<<G1, 256, 0, stream>>>(ei, E, N, sbcnt, sbdata);
        part2_kernel<<<NSB * BPS, 256, 0, stream>>>(sbdata, sbcnt, bcnt, boff, pk);
        gemm1_kernel<<<(N + 15) / 16, 256, 0, stream>>>(x, W1, a_s1, a_d1, h1, sp1, ed1, N);
    } else {
        gemm1_kernel<<<(N + 15) / 16, 256, 0, stream>>>(x, W1, a_s1, a_d1, h1, sp1, ed1, N);
        bhist_kernel<<<256, 256, 0, stream>>>(ei, E, N, bcnt, NB);
        bscan_kernel<<<1, 64, 0, stream>>>(bcnt, NB, boff, bcur);
        bscat_kernel<<<256, 256, 0, stream>>>(ei, E, N, bcur, pk, NB);
    }
    edge1_gather<<<egrid, 256, 0, stream>>>(bcnt, boff, pk, sp1, ed1, h1, o1,
                                            ctrs + 0, NB, N);
    gemm2_kernel<<<(N + 7) / 8, 256, 0, stream>>>(o1, b1, W2, a_s2, a_d2, Wr, rec, ed2, N);
    edge2_gather<<<egrid, 256, 0, stream>>>(bcnt, boff, pk, rec, ed2, b2, Wr, pooled,
                                            ctrs + 1, NB, N);
    final_kernel<<<1, 64, 0, stream>>>(pooled, br, out);
}

// Round 8
// 374.264 us; speedup vs baseline: 1.3326x; 1.2146x over previous
//
#include <hip/hip_runtime.h>
#include <math.h>

#define NEG_SLOPE 0.2f
#define FIN 128
#define H1 8
#define F1 64   // HEADS1*HID
#define F2 32   // OUT2

#define SHIFT 5
#define BW 32          // dsts per bucket
#define CAPL 2048      // LDS edge slots per bucket (mean ~1056, sigma ~32)
#define CAP_G 1408     // static pk slots per bucket (mean+11sigma)
#define NBMAX 4096

// two-pass radix partition (write-coalescing fix for the 7x write amplification)
#define SB_SHIFT 11            // 2048 nodes per super-bucket = 64 final buckets
#define NSBMAX 64              // supports N <= 131072
#define P_CHUNK 2048           // edges per partition block
#define BPS 35                 // pass-2 blocks per SB
#define SBCAP (BPS * P_CHUNK)  // slots per SB in sbdata

typedef unsigned short ushort_t;
typedef unsigned int uint_t;

#define LO16(u) __uint_as_float((u) << 16)
#define HI16(u) __uint_as_float((u) & 0xffff0000u)

// fold across the 4 edge slots (lane bits 4..5) -- R3-proven edge1 shape
#define FOLDQ4(x) { x += __shfl_xor(x, 16, 64); x += __shfl_xor(x, 32, 64); }
// fold across all 64 lanes
#define FOLD64(x) { x += __shfl_xor(x, 1, 64); x += __shfl_xor(x, 2, 64); x += __shfl_xor(x, 4, 64); \
                    x += __shfl_xor(x, 8, 64); x += __shfl_xor(x, 16, 64); x += __shfl_xor(x, 32, 64); }

static __device__ __forceinline__ ushort_t f2bf(float f) {
    uint_t u = __float_as_uint(f);
    u = (u + 0x7FFFu + ((u >> 16) & 1u)) >> 16; // RNE
    return (ushort_t)u;
}
// pack {A=exp(e), B=exp(0.2e)} as bf16x2: A in low 16, B in high 16
static __device__ __forceinline__ uint_t packAB(float e) {
    return (uint_t)f2bf(__expf(e)) | ((uint_t)f2bf(__expf(NEG_SLOPE * e)) << 16);
}

// ---------------- Layer-1 GEMM: h1 = x @ W1 (bf16 out), fused exp-tables -----
__global__ void gemm1_kernel(const float* __restrict__ x, const float* __restrict__ W1,
                             const float* __restrict__ a_src, const float* __restrict__ a_dst,
                             ushort_t* __restrict__ h1, uint_t* __restrict__ sp,
                             float* __restrict__ ed, int N) {
    __shared__ float xs[16][FIN]; // 8 KB
    int tid = threadIdx.x;
    int n0 = blockIdx.x * 16;
    for (int i = tid; i < 16 * FIN; i += 256) {
        int nn = n0 + (i >> 7);
        xs[i >> 7][i & 127] = (nn < N) ? x[(size_t)nn * FIN + (i & 127)] : 0.f;
    }
    __syncthreads();
    int wv = tid >> 6, j = tid & 63;
    int nb = wv << 2;
    float a0 = 0.f, a1 = 0.f, a2 = 0.f, a3 = 0.f;
#pragma unroll 2
    for (int k = 0; k < FIN; k += 4) {
        float w0 = W1[(k + 0) * F1 + j];
        float w1 = W1[(k + 1) * F1 + j];
        float w2 = W1[(k + 2) * F1 + j];
        float w3 = W1[(k + 3) * F1 + j];
        float4 x0 = *(const float4*)&xs[nb + 0][k];
        float4 x1 = *(const float4*)&xs[nb + 1][k];
        float4 x2 = *(const float4*)&xs[nb + 2][k];
        float4 x3 = *(const float4*)&xs[nb + 3][k];
        a0 = fmaf(x0.x, w0, fmaf(x0.y, w1, fmaf(x0.z, w2, fmaf(x0.w, w3, a0))));
        a1 = fmaf(x1.x, w0, fmaf(x1.y, w1, fmaf(x1.z, w2, fmaf(x1.w, w3, a1))));
        a2 = fmaf(x2.x, w0, fmaf(x2.y, w1, fmaf(x2.z, w2, fmaf(x2.w, w3, a2))));
        a3 = fmaf(x3.x, w0, fmaf(x3.y, w1, fmaf(x3.z, w2, fmaf(x3.w, w3, a3))));
    }
    float as = a_src[j], ad = a_dst[j];
    float av[4] = {a0, a1, a2, a3};
#pragma unroll
    for (int t = 0; t < 4; ++t) {
        int n = n0 + nb + t;
        if (n >= N) break;
        h1[(size_t)n * F1 + j] = f2bf(av[t]);
        float vs = av[t] * as;
        float vd = av[t] * ad;
#pragma unroll
        for (int off = 4; off >= 1; off >>= 1) {
            vs += __shfl_down(vs, off, 8);
            vd += __shfl_down(vd, off, 8);
        }
        if ((j & 7) == 0) {
            sp[n * H1 + (j >> 3)] = packAB(vs);
            ed[n * H1 + (j >> 3)] = vd;
        }
    }
}

// ---------------- init: counters, dummy node (padding target for edge2) ------
__global__ void zerob_kernel(int* __restrict__ bcnt, int* __restrict__ boff,
                             int NB, float* __restrict__ pooled, int capg,
                             int* __restrict__ sbcnt, int nsb,
                             uint_t* __restrict__ sp1, ushort_t* __restrict__ h1, int N) {
    int t = blockIdx.x * blockDim.x + threadIdx.x;
    int stride = gridDim.x * blockDim.x;
    for (int i = t; i < NB; i += stride) {
        bcnt[i] = 0;
        if (capg) boff[i] = i * capg;
    }
    for (int i = t; i < nsb; i += stride) sbcnt[i] = 0;
    if (t < H1) sp1[(size_t)N * H1 + t] = 0u;              // dummy: weight == 0
    if (t >= 8 && t < 8 + F1) h1[(size_t)N * F1 + (t - 8)] = 0; // dummy: finite row
    if (t == 72) pooled[0] = 0.f;
}

// ---------------- Pass 1: partition edges into super-buckets (coalesced) -----
__global__ void __launch_bounds__(256, 4)
part1_kernel(const int* __restrict__ ei, int E, int N,
             int* __restrict__ sbcnt, uint_t* __restrict__ sbdata) {
    __shared__ int hist[NSBMAX];
    __shared__ int loff[NSBMAX];
    __shared__ int lcur[NSBMAX];
    __shared__ int gb[NSBMAX];
    __shared__ uint_t buf[P_CHUNK];
    __shared__ unsigned char sbarr[P_CHUNK];
    int tid = threadIdx.x;
    int NSB = (N + ((1 << SB_SHIFT) - 1)) >> SB_SHIFT;
    for (int i = tid; i < NSB; i += 256) hist[i] = 0;
    __syncthreads();
    int EN = E + N;
    int base = blockIdx.x * P_CHUNK;
    int m = EN - base; if (m > P_CHUNK) m = P_CHUNK;
    int t0 = base + tid * 8;
    int s[8], d[8];
    bool fast = (t0 + 8 <= E) && ((E & 3) == 0);
    if (fast) {
        int4 a = *(const int4*)&ei[t0];
        int4 b = *(const int4*)&ei[t0 + 4];
        s[0]=a.x; s[1]=a.y; s[2]=a.z; s[3]=a.w; s[4]=b.x; s[5]=b.y; s[6]=b.z; s[7]=b.w;
        int4 c = *(const int4*)&ei[E + t0];
        int4 e2 = *(const int4*)&ei[E + t0 + 4];
        d[0]=c.x; d[1]=c.y; d[2]=c.z; d[3]=c.w; d[4]=e2.x; d[5]=e2.y; d[6]=e2.z; d[7]=e2.w;
    } else {
#pragma unroll
        for (int r = 0; r < 8; ++r) {
            int t = t0 + r;
            if (t < EN) {
                if (t < E) { s[r] = ei[t]; d[r] = ei[E + t]; }
                else       { s[r] = d[r] = t - E; }
            } else d[r] = -1;
        }
    }
#pragma unroll
    for (int r = 0; r < 8; ++r)
        if (d[r] >= 0) atomicAdd(&hist[d[r] >> SB_SHIFT], 1);
    __syncthreads();
    if (tid < 64) {
        int v = (tid < NSB) ? hist[tid] : 0;
        int e = v;
#pragma unroll
        for (int o = 1; o < 64; o <<= 1) {
            int u = __shfl_up(e, o, 64);
            if (tid >= o) e += u;
        }
        e -= v; // exclusive prefix
        if (tid < NSB) {
            loff[tid] = e;
            lcur[tid] = e;
            gb[tid] = v ? atomicAdd(&sbcnt[tid], v) : 0;
        }
    }
    __syncthreads();
#pragma unroll
    for (int r = 0; r < 8; ++r)
        if (d[r] >= 0) {
            int sb = d[r] >> SB_SHIFT;
            int pos = atomicAdd(&lcur[sb], 1);
            buf[pos] = ((uint_t)s[r] << SB_SHIFT) | (uint_t)(d[r] & ((1 << SB_SHIFT) - 1));
            sbarr[pos] = (unsigned char)sb;
        }
    __syncthreads();
    for (int i = tid; i < m; i += 256) {
        int sb = sbarr[i];
        int idx = gb[sb] + (i - loff[sb]);
        if (idx < SBCAP)
            sbdata[(size_t)sb * SBCAP + idx] = buf[i];
    }
}

// ---------------- Pass 2: scatter within SB to final pk buckets (coalesced) --
__global__ void __launch_bounds__(256, 4)
part2_kernel(const uint_t* __restrict__ sbdata, const int* __restrict__ sbcnt,
             int* __restrict__ bcnt, const int* __restrict__ boff,
             uint_t* __restrict__ pk) {
    __shared__ int hist[64];
    __shared__ int loff[64];
    __shared__ int lcur[64];
    __shared__ int gb[64];
    __shared__ uint_t buf[P_CHUNK];
    int tid = threadIdx.x;
    int sb = blockIdx.x / BPS;
    int base = (blockIdx.x % BPS) * P_CHUNK;
    int cnt = sbcnt[sb];
    if (cnt > SBCAP) cnt = SBCAP;
    if (base >= cnt) return;
    int m = cnt - base; if (m > P_CHUNK) m = P_CHUNK;
    if (tid < 64) hist[tid] = 0;
    __syncthreads();
    const uint_t* src = sbdata + (size_t)sb * SBCAP + base;
    uint_t v[8];
#pragma unroll
    for (int r = 0; r < 8; ++r) {
        int i = tid + r * 256; // coalesced strided read
        if (i < m) {
            v[r] = src[i];
            atomicAdd(&hist[(v[r] >> 5) & 63], 1);
        }
    }
    __syncthreads();
    if (tid < 64) {
        int c = hist[tid];
        int e = c;
#pragma unroll
        for (int o = 1; o < 64; o <<= 1) {
            int u = __shfl_up(e, o, 64);
            if (tid >= o) e += u;
        }
        e -= c;
        loff[tid] = e;
        lcur[tid] = e;
        int bucket = (sb << 6) + tid;
        gb[tid] = c ? (boff[bucket] + atomicAdd(&bcnt[bucket], c)) : 0;
    }
    __syncthreads();
#pragma unroll
    for (int r = 0; r < 8; ++r) {
        int i = tid + r * 256;
        if (i < m) {
            int lb = (v[r] >> 5) & 63;
            int pos = atomicAdd(&lcur[lb], 1);
            buf[pos] = v[r];
        }
    }
    __syncthreads();
    for (int i = tid; i < m; i += 256) {
        uint_t u = buf[i];
        int lb = (u >> 5) & 63;
        int idx = gb[lb] + (i - loff[lb]);
        pk[idx] = ((u >> SB_SHIFT) << SHIFT) | (u & (BW - 1));
    }
}

// ---- exact-CSR fallback path (used only when ws_size too small for static) --
__global__ void bhist_kernel(const int* __restrict__ ei, int E, int N,
                             int* __restrict__ bcnt, int NB) {
    __shared__ int h[NBMAX];
    int tid = threadIdx.x;
    for (int i = tid; i < NB; i += 256) h[i] = 0;
    __syncthreads();
    int EN = E + N;
    int chunk = (EN + gridDim.x - 1) / gridDim.x;
    int e0 = blockIdx.x * chunk;
    int e1 = e0 + chunk; if (e1 > EN) e1 = EN;
    for (int t = e0 + tid; t < e1; t += 256) {
        int d = (t < E) ? ei[E + t] : (t - E);
        atomicAdd(&h[d >> SHIFT], 1);
    }
    __syncthreads();
    for (int i = tid; i < NB; i += 256)
        if (h[i]) atomicAdd(&bcnt[i], h[i]);
}

__global__ void bscan_kernel(const int* __restrict__ bcnt, int NB,
                             int* __restrict__ boff, int* __restrict__ bcur) {
    int lane = threadIdx.x; // 0..63
    int chunk = (NB + 63) >> 6;
    int lo = lane * chunk;
    int hi = lo + chunk; if (hi > NB) hi = NB;
    int sum = 0;
    for (int i = lo; i < hi; ++i) sum += bcnt[i];
    int e = sum;
#pragma unroll
    for (int o = 1; o < 64; o <<= 1) {
        int v = __shfl_up(e, o, 64);
        if (lane >= o) e += v;
    }
    e -= sum;
    int run = e;
    for (int i = lo; i < hi; ++i) {
        int c = bcnt[i];
        boff[i] = run;
        bcur[i] = run;
        run += c;
    }
}

__global__ void bscat_kernel(const int* __restrict__ ei, int E, int N,
                             int* __restrict__ bcur, uint_t* __restrict__ pk, int NB) {
    __shared__ int lh[NBMAX];
    __shared__ int lc[NBMAX];
    int tid = threadIdx.x;
    for (int i = tid; i < NB; i += 256) lh[i] = 0;
    __syncthreads();
    int EN = E + N;
    int chunk = (EN + gridDim.x - 1) / gridDim.x;
    int e0 = blockIdx.x * chunk;
    int e1 = e0 + chunk; if (e1 > EN) e1 = EN;
    for (int t = e0 + tid; t < e1; t += 256) {
        int d = (t < E) ? ei[E + t] : (t - E);
        atomicAdd(&lh[d >> SHIFT], 1);
    }
    __syncthreads();
    for (int i = tid; i < NB; i += 256) {
        int c = lh[i];
        lc[i] = c ? atomicAdd(&bcur[i], c) : 0;
    }
    __syncthreads();
    for (int t = e0 + tid; t < e1; t += 256) {
        int s, d;
        if (t < E) { s = ei[t]; d = ei[E + t]; } else { s = d = t - E; }
        int pos = atomicAdd(&lc[d >> SHIFT], 1);
        pk[pos] = ((uint_t)s << SHIFT) | (uint_t)(d & (BW - 1));
    }
}

// ---------------- Layer-1 edge pass: R3-proven body, per-bucket launch -------
// R7 lesson: per-bucket launch (blockIdx = bucket) beats persistent blocks by
// ~40% here -- fresh blocks stagger the barrier-heavy LDS build against other
// blocks' gather phases; persistent blocks phase-lock and drain the mem queue.
__global__ void __launch_bounds__(256, 8)
edge1_gather(const int* __restrict__ bcnt, const int* __restrict__ boff,
             const uint_t* __restrict__ pk,
             const uint_t* __restrict__ sp, const float* __restrict__ ed,
             const ushort_t* __restrict__ h1, float* __restrict__ o1, int N) {
    int b = blockIdx.x;
    int d0 = b << SHIFT;
    int cnt = bcnt[b];
    int gbase = boff[b];
    int tid = threadIdx.x;
    int wv = tid >> 6;
    int L = tid & 63;
    int q = L >> 4;           // edge slot 0..3
    int c4 = (L & 15) << 2;   // channel base
    int hL = (L & 15) >> 1;   // head of channels c4..c4+3
    __shared__ int ldeg[BW], loff[BW], lcur[BW];
    __shared__ int lsrc[CAPL];
    if (cnt <= CAPL) {
        if (tid < BW) ldeg[tid] = 0;
        __syncthreads();
        for (int k = tid; k < cnt; k += 256) atomicAdd(&ldeg[pk[gbase + k] & (BW - 1)], 1);
        __syncthreads();
        if (tid < BW) {
            int v = ldeg[tid];
            int e = v;
#pragma unroll
            for (int o = 1; o < BW; o <<= 1) {
                int u = __shfl_up(e, o, 64);
                if (tid >= o) e += u;
            }
            e -= v;
            loff[tid] = e;
            lcur[tid] = e;
        }
        __syncthreads();
        for (int k = tid; k < cnt; k += 256) {
            uint_t v = pk[gbase + k];
            int pos = atomicAdd(&lcur[v & (BW - 1)], 1);
            lsrc[pos] = (int)(v >> SHIFT);
        }
        __syncthreads();
        for (int ld = wv * 8; ld < wv * 8 + 8; ++ld) {
            int d = d0 + ld;
            if (d >= N) break;
            int st = loff[ld], en = st + ldeg[ld];
            float edv = ed[d * H1 + hL];
            float Ad = __expf(edv), Bd = __expf(NEG_SLOPE * edv);
            float ax = 0.f, ay = 0.f, az = 0.f, aw = 0.f, wsum = 0.f;
            uint_t U0, U1; uint2 V0, V1;
            {
                int i0 = st + q, i1 = st + 4 + q;
                bool ok0 = i0 < en, ok1 = i1 < en;
                int s0 = lsrc[ok0 ? i0 : st];   // st valid: self-loop => en>st
                int s1 = lsrc[ok1 ? i1 : st];
                uint_t u0 = sp[s0 * H1 + hL];
                uint_t u1 = sp[s1 * H1 + hL];
                V0 = *(const uint2*)(h1 + ((size_t)s0 << 6) + c4);
                V1 = *(const uint2*)(h1 + ((size_t)s1 << 6) + c4);
                U0 = ok0 ? u0 : 0u;
                U1 = ok1 ? u1 : 0u;
            }
            for (int k = st; k < en; k += 8) {
                uint_t N0, N1; uint2 P0, P1;
                {
                    int i0 = k + 8 + q, i1 = k + 12 + q;
                    bool ok0 = i0 < en, ok1 = i1 < en;
                    int s0 = lsrc[ok0 ? i0 : st];
                    int s1 = lsrc[ok1 ? i1 : st];
                    uint_t u0 = sp[s0 * H1 + hL];
                    uint_t u1 = sp[s1 * H1 + hL];
                    P0 = *(const uint2*)(h1 + ((size_t)s0 << 6) + c4);
                    P1 = *(const uint2*)(h1 + ((size_t)s1 << 6) + c4);
                    N0 = ok0 ? u0 : 0u;
                    N1 = ok1 ? u1 : 0u;
                }
                float w0 = fmaxf(LO16(U0) * Ad, HI16(U0) * Bd);
                float w1 = fmaxf(LO16(U1) * Ad, HI16(U1) * Bd);
                ax = fmaf(w0, LO16(V0.x), ax);
                ay = fmaf(w0, HI16(V0.x), ay);
                az = fmaf(w0, LO16(V0.y), az);
                aw = fmaf(w0, HI16(V0.y), aw);
                ax = fmaf(w1, LO16(V1.x), ax);
                ay = fmaf(w1, HI16(V1.x), ay);
                az = fmaf(w1, LO16(V1.y), az);
                aw = fmaf(w1, HI16(V1.y), aw);
                wsum += w0 + w1;
                U0 = N0; U1 = N1; V0 = P0; V1 = P1;
            }
            FOLDQ4(ax); FOLDQ4(ay); FOLDQ4(az); FOLDQ4(aw); FOLDQ4(wsum);
            if (q == 0) {
                float inv = 1.f / wsum;
                float4 r; r.x = ax * inv; r.y = ay * inv; r.z = az * inv; r.w = aw * inv;
                *(float4*)(o1 + (size_t)d * F1 + c4) = r;
            }
        }
    } else {
        // statistically unreachable fallback: masked whole-bucket scan
        for (int ld = wv * 8; ld < wv * 8 + 8; ++ld) {
            int d = d0 + ld;
            if (d >= N) break;
            float edv = ed[d * H1 + hL];
            float Ad = __expf(edv), Bd = __expf(NEG_SLOPE * edv);
            float ax = 0.f, ay = 0.f, az = 0.f, aw = 0.f, wsum = 0.f;
            for (int k0 = 0; k0 < cnt; k0 += 4) {
                int idx = k0 + q;
                bool ok = idx < cnt;
                uint_t v = pk[gbase + (ok ? idx : 0)];
                int s = (int)(v >> SHIFT);
                bool m = ok && ((int)(v & (BW - 1)) == ld);
                uint_t u = sp[(uint_t)s * H1 + hL];
                float w = m ? fmaxf(LO16(u) * Ad, HI16(u) * Bd) : 0.f;
                uint2 hv = *(const uint2*)(h1 + ((size_t)s << 6) + c4);
                ax = fmaf(w, LO16(hv.x), ax);
                ay = fmaf(w, HI16(hv.x), ay);
                az = fmaf(w, LO16(hv.y), az);
                aw = fmaf(w, HI16(hv.y), aw);
                wsum += w;
            }
            FOLDQ4(ax); FOLDQ4(ay); FOLDQ4(az); FOLDQ4(aw); FOLDQ4(wsum);
            if (q == 0) {
                float inv = 1.f / wsum;
                float4 r; r.x = ax * inv; r.y = ay * inv; r.z = az * inv; r.w = aw * inv;
                *(float4*)(o1 + (size_t)d * F1 + c4) = r;
            }
        }
    }
}

// ---------------- Layer-2 GEMM: folds Wr projection -> 8-B record per node ---
// rec[n] = { packAB(e_src2), g = (a1@W2 row) . Wr }  (g in f32, no bf16 loss)
__global__ void gemm2_kernel(const float* __restrict__ o1, const float* __restrict__ b1,
                             const float* __restrict__ W2,
                             const float* __restrict__ a_src2, const float* __restrict__ a_dst2,
                             const float* __restrict__ Wr,
                             uint2* __restrict__ rec, float* __restrict__ ed2, int N) {
    if (blockIdx.x == 0 && threadIdx.x == 0) {
        uint2 z; z.x = 0u; z.y = 0u;
        rec[N] = z;                     // dummy node: w==0, g==0
    }
    int half = threadIdx.x >> 5;
    int n = blockIdx.x * 8 + half;
    int j = threadIdx.x & 31;
    __shared__ float a1s[8][F1];
    if (n < N) {
#pragma unroll
        for (int r = 0; r < 2; ++r) {
            int k = r * 32 + j;
            float v = o1[(size_t)n * F1 + k] + b1[k];
            a1s[half][k] = v > 0.f ? v : expm1f(v); // ELU
        }
    }
    __syncthreads();
    if (n >= N) return;
    float acc = 0.f;
#pragma unroll
    for (int k = 0; k < F1; ++k) acc = fmaf(a1s[half][k], W2[k * F2 + j], acc);
    float vs = acc * a_src2[j];
    float vd = acc * a_dst2[j];
    float vg = acc * Wr[j];
#pragma unroll
    for (int off = 16; off >= 1; off >>= 1) {
        vs += __shfl_down(vs, off, 32);
        vd += __shfl_down(vd, off, 32);
        vg += __shfl_down(vg, off, 32);
    }
    if (j == 0) {
        uint2 r; r.x = packAB(vs); r.y = __float_as_uint(vg);
        rec[n] = r;
        ed2[n] = vd;
    }
}

// ---------------- Layer-2 edge pass: scalar gather, per-bucket launch --------
__global__ void __launch_bounds__(256, 8)
edge2_gather(const int* __restrict__ bcnt, const int* __restrict__ boff,
             const uint_t* __restrict__ pk,
             const uint2* __restrict__ rec, const float* __restrict__ ed2,
             const float* __restrict__ b2, const float* __restrict__ Wr,
             float* __restrict__ pooled, int N) {
    int b = blockIdx.x;
    int d0 = b << SHIFT;
    int cnt = bcnt[b];
    int gbase = boff[b];
    int tid = threadIdx.x;
    int wv = tid >> 6;
    int L = tid & 63;
    __shared__ int ldeg[BW], loff[BW], ldgp[BW], lcur[BW];
    __shared__ int lsrc[CAPL];
    __shared__ float ls[4];
    float t0 = (L < F2) ? b2[L] * Wr[L] : 0.f;
    FOLD64(t0);
    float b2w = t0;          // dot(b2, Wr), identical on all lanes
    float part = 0.f;
    if (cnt <= CAPL - 8 * BW - 16) {
        if (tid < BW) ldeg[tid] = 0;
        __syncthreads();
        for (int k = tid; k < cnt; k += 256) atomicAdd(&ldeg[pk[gbase + k] & (BW - 1)], 1);
        __syncthreads();
        if (tid < BW) {
            int v = ldeg[tid];
            int vp = (v + 7) & ~7;
            int e = vp;
#pragma unroll
            for (int o = 1; o < BW; o <<= 1) {
                int u = __shfl_up(e, o, 64);
                if (tid >= o) e += u;
            }
            e -= vp;
            loff[tid] = e;
            lcur[tid] = e;
            ldgp[tid] = vp;
        }
        __syncthreads();
        int tot = loff[BW - 1] + ldgp[BW - 1];
        for (int k = tid; k < tot + 16; k += 256) lsrc[k] = N;
        __syncthreads();
        for (int k = tid; k < cnt; k += 256) {
            uint_t v = pk[gbase + k];
            int pos = atomicAdd(&lcur[v & (BW - 1)], 1);
            lsrc[pos] = (int)(v >> SHIFT);
        }
        __syncthreads();
        for (int ld = wv * 8; ld < wv * 8 + 8; ++ld) {
            int d = d0 + ld;
            if (d >= N) break;
            int st = loff[ld], en = st + ldgp[ld];
            float edv = ed2[d];
            float Ad = __expf(edv), Bd = __expf(NEG_SLOPE * edv);
            float acc = 0.f, wsm = 0.f;
            for (int k = st; k < en; k += 64) {
                int i = k + L;
                bool ok = i < en;
                int s = lsrc[ok ? i : st];
                uint2 r = rec[s];
                float w = ok ? fmaxf(LO16(r.x) * Ad, HI16(r.x) * Bd) : 0.f;
                acc = fmaf(w, __uint_as_float(r.y), acc);
                wsm += w;
            }
            FOLD64(acc); FOLD64(wsm);
            part += acc / wsm + b2w;   // identical on all lanes; lane 0 used below
        }
    } else {
        for (int ld = wv * 8; ld < wv * 8 + 8; ++ld) {
            int d = d0 + ld;
            if (d >= N) break;
            float edv = ed2[d];
            float Ad = __expf(edv), Bd = __expf(NEG_SLOPE * edv);
            float acc = 0.f, wsm = 0.f;
            for (int k0 = 0; k0 < cnt; k0 += 64) {
                int i = k0 + L;
                bool ok = i < cnt;
                uint_t v = pk[gbase + (ok ? i : 0)];
                int s = (int)(v >> SHIFT);
                bool mm = ok && ((int)(v & (BW - 1)) == ld);
                uint2 r = rec[s];
                float w = mm ? fmaxf(LO16(r.x) * Ad, HI16(r.x) * Bd) : 0.f;
                acc = fmaf(w, __uint_as_float(r.y), acc);
                wsm += w;
            }
            FOLD64(acc); FOLD64(wsm);
            part += acc / wsm + b2w;
        }
    }
    if (L == 0) ls[wv] = part;
    __syncthreads();
    if (tid == 0) atomicAdd(pooled, ls[0] + ls[1] + ls[2] + ls[3]);
}

__global__ void final_kernel(const float* __restrict__ pooled, const float* __restrict__ br,
                             float* __restrict__ out) {
    if (threadIdx.x == 0 && blockIdx.x == 0) out[0] = pooled[0] + br[0];
}

static inline size_t al128(size_t v) { return (v + 127) & ~(size_t)127; }

extern "C" void kernel_launch(void* const* d_in, const int* in_sizes, int n_in,
                              void* d_out, int out_size, void* d_ws, size_t ws_size,
                              hipStream_t stream) {
    const float* x    = (const float*)d_in[0];
    const int*   ei   = (const int*)d_in[1];
    const float* W1   = (const float*)d_in[2];
    const float* a_s1 = (const float*)d_in[3];
    const float* a_d1 = (const float*)d_in[4];
    const float* b1   = (const float*)d_in[5];
    const float* W2   = (const float*)d_in[6];
    const float* a_s2 = (const float*)d_in[7];
    const float* a_d2 = (const float*)d_in[8];
    const float* b2   = (const float*)d_in[9];
    const float* Wr   = (const float*)d_in[10];
    const float* br   = (const float*)d_in[11];
    float* out = (float*)d_out;

    int N = in_sizes[0] / FIN;
    int E = in_sizes[1] / 2;
    size_t n = (size_t)N;
    int NB = (N + BW - 1) >> SHIFT;
    int NSB = (N + ((1 << SB_SHIFT) - 1)) >> SB_SHIFT;

    // workspace layout (bytes); all hot arrays 128-B aligned.
    // CRITICAL: h1 rows are 128 B and gathered randomly -- h1 base MUST be
    // 128-aligned or every row straddles two cache lines (R4: FETCH +64%).
    char* ws = (char*)d_ws;
    size_t off_o1  = 0;                                   // 256N
    size_t off_sp1 = al128(off_o1 + n * 256);             // 32N + 32 (dummy row)
    size_t off_ed1 = al128(off_sp1 + n * 32 + 32);        // 32N
    size_t off_h1  = al128(off_ed1 + n * 32);             // 128N + 128 (dummy row)
    size_t off_pk  = al128(off_h1 + n * 128 + 128);
    float*    o1   = (float*)(ws + off_o1);
    uint_t*   sp1  = (uint_t*)(ws + off_sp1);
    float*    ed1  = (float*)(ws + off_ed1);
    ushort_t* h1   = (ushort_t*)(ws + off_h1);
    uint_t*   pk   = (uint_t*)(ws + off_pk);
    size_t pk_static = (size_t)NB * CAP_G * 4;            // ~17.6 MB
    size_t pk_exact  = (size_t)(E + N) * 4;               // ~13.2 MB
    // sbdata overlays o1 (disjoint lifetimes)
    uint_t* sbdata = (uint_t*)ws;
    bool use_static = (NSB <= NSBMAX) &&
                      ((size_t)NSB * SBCAP * 4 <= n * 256) &&
                      (ws_size >= off_pk + pk_static + (size_t)NBMAX * 16 +
                                  (size_t)NSBMAX * 4 + 128);
    char* tail = ws + off_pk + (use_static ? pk_static : pk_exact);
    int*      bcnt  = (int*)tail;                         // NBMAX int
    int*      boff  = (int*)(tail + NBMAX * 4);           // NBMAX int
    int*      bcur  = (int*)(tail + NBMAX * 8);           // NBMAX int
    int*      sbcnt = (int*)(tail + NBMAX * 12);          // NSBMAX int
    float*  pooled  = (float*)(tail + NBMAX * 12 + NSBMAX * 4); // 1 f32
    // layer-2 overlays (dead after edge1): rec over h1, ed2 over ed1
    uint2* rec = (uint2*)h1;
    float* ed2 = ed1;

    zerob_kernel<<<8, 256, 0, stream>>>(bcnt, boff, NB, pooled,
                                        use_static ? CAP_G : 0, sbcnt, NSB,
                                        sp1, h1, N);
    if (use_static) {
        int EN = E + N;
        int G1 = (EN + P_CHUNK - 1) / P_CHUNK;
        part1_kernel<<<G1, 256, 0, stream>>>(ei, E, N, sbcnt, sbdata);
        part2_kernel<<<NSB * BPS, 256, 0, stream>>>(sbdata, sbcnt, bcnt, boff, pk);
        gemm1_kernel<<<(N + 15) / 16, 256, 0, stream>>>(x, W1, a_s1, a_d1, h1, sp1, ed1, N);
    } else {
        gemm1_kernel<<<(N + 15) / 16, 256, 0, stream>>>(x, W1, a_s1, a_d1, h1, sp1, ed1, N);
        bhist_kernel<<<256, 256, 0, stream>>>(ei, E, N, bcnt, NB);
        bscan_kernel<<<1, 64, 0, stream>>>(bcnt, NB, boff, bcur);
        bscat_kernel<<<256, 256, 0, stream>>>(ei, E, N, bcur, pk, NB);
    }
    edge1_gather<<<NB, 256, 0, stream>>>(bcnt, boff, pk, sp1, ed1, h1, o1, N);
    gemm2_kernel<<<(N + 7) / 8, 256, 0, stream>>>(o1, b1, W2, a_s2, a_d2, Wr, rec, ed2, N);
    edge2_gather<<<NB, 256, 0, stream>>>(bcnt, boff, pk, rec, ed2, b2, Wr, pooled, N);
    final_kernel<<<1, 64, 0, stream>>>(pooled, br, out);
}

// Round 10
// 372.701 us; speedup vs baseline: 1.3382x; 1.0042x over previous
//
#include <hip/hip_runtime.h>
#include <math.h>

#define NEG_SLOPE 0.2f
#define FIN 128
#define H1 8
#define F1 64   // HEADS1*HID
#define F2 32   // OUT2

#define SHIFT 5
#define BW 32          // dsts per bucket
#define CAPL 2048      // LDS edge slots per bucket (mean ~1056, sigma ~32)
#define CAP_G 1408     // static pk slots per bucket (mean+11sigma)
#define NBMAX 4096

// two-pass radix partition (write-coalescing fix for the 7x write amplification)
#define SB_SHIFT 11            // 2048 nodes per super-bucket = 64 final buckets
#define NSBMAX 64              // supports N <= 131072
#define P_CHUNK 2048           // edges per partition block
#define BPS 35                 // pass-2 blocks per SB
#define SBCAP (BPS * P_CHUNK)  // slots per SB in sbdata

typedef unsigned short ushort_t;
typedef unsigned int uint_t;

#define LO16(u) __uint_as_float((u) << 16)
#define HI16(u) __uint_as_float((u) & 0xffff0000u)

// fold across the 4 edge slots (lane bits 4..5) -- R3-proven edge1 shape
#define FOLDQ4(x) { x += __shfl_xor(x, 16, 64); x += __shfl_xor(x, 32, 64); }
// fold across all 64 lanes (leaves the TOTAL in every lane -- lane-uniform!)
#define FOLD64(x) { x += __shfl_xor(x, 1, 64); x += __shfl_xor(x, 2, 64); x += __shfl_xor(x, 4, 64); \
                    x += __shfl_xor(x, 8, 64); x += __shfl_xor(x, 16, 64); x += __shfl_xor(x, 32, 64); }

static __device__ __forceinline__ ushort_t f2bf(float f) {
    uint_t u = __float_as_uint(f);
    u = (u + 0x7FFFu + ((u >> 16) & 1u)) >> 16; // RNE
    return (ushort_t)u;
}
// pack {A=exp(e), B=exp(0.2e)} as bf16x2: A in low 16, B in high 16
static __device__ __forceinline__ uint_t packAB(float e) {
    return (uint_t)f2bf(__expf(e)) | ((uint_t)f2bf(__expf(NEG_SLOPE * e)) << 16);
}

// ---------------- Layer-1 GEMM: h1 = x @ W1 (bf16 out), fused exp-tables -----
__global__ void gemm1_kernel(const float* __restrict__ x, const float* __restrict__ W1,
                             const float* __restrict__ a_src, const float* __restrict__ a_dst,
                             ushort_t* __restrict__ h1, uint_t* __restrict__ sp,
                             float* __restrict__ ed, int N) {
    __shared__ float xs[16][FIN]; // 8 KB
    int tid = threadIdx.x;
    int n0 = blockIdx.x * 16;
    for (int i = tid; i < 16 * FIN; i += 256) {
        int nn = n0 + (i >> 7);
        xs[i >> 7][i & 127] = (nn < N) ? x[(size_t)nn * FIN + (i & 127)] : 0.f;
    }
    __syncthreads();
    int wv = tid >> 6, j = tid & 63;
    int nb = wv << 2;
    float a0 = 0.f, a1 = 0.f, a2 = 0.f, a3 = 0.f;
#pragma unroll 2
    for (int k = 0; k < FIN; k += 4) {
        float w0 = W1[(k + 0) * F1 + j];
        float w1 = W1[(k + 1) * F1 + j];
        float w2 = W1[(k + 2) * F1 + j];
        float w3 = W1[(k + 3) * F1 + j];
        float4 x0 = *(const float4*)&xs[nb + 0][k];
        float4 x1 = *(const float4*)&xs[nb + 1][k];
        float4 x2 = *(const float4*)&xs[nb + 2][k];
        float4 x3 = *(const float4*)&xs[nb + 3][k];
        a0 = fmaf(x0.x, w0, fmaf(x0.y, w1, fmaf(x0.z, w2, fmaf(x0.w, w3, a0))));
        a1 = fmaf(x1.x, w0, fmaf(x1.y, w1, fmaf(x1.z, w2, fmaf(x1.w, w3, a1))));
        a2 = fmaf(x2.x, w0, fmaf(x2.y, w1, fmaf(x2.z, w2, fmaf(x2.w, w3, a2))));
        a3 = fmaf(x3.x, w0, fmaf(x3.y, w1, fmaf(x3.z, w2, fmaf(x3.w, w3, a3))));
    }
    float as = a_src[j], ad = a_dst[j];
    float av[4] = {a0, a1, a2, a3};
#pragma unroll
    for (int t = 0; t < 4; ++t) {
        int n = n0 + nb + t;
        if (n >= N) break;
        h1[(size_t)n * F1 + j] = f2bf(av[t]);
        float vs = av[t] * as;
        float vd = av[t] * ad;
#pragma unroll
        for (int off = 4; off >= 1; off >>= 1) {
            vs += __shfl_down(vs, off, 8);
            vd += __shfl_down(vd, off, 8);
        }
        if ((j & 7) == 0) {
            sp[n * H1 + (j >> 3)] = packAB(vs);
            ed[n * H1 + (j >> 3)] = vd;
        }
    }
}

// ---------------- init ------------------------------------------------------
__global__ void zerob_kernel(int* __restrict__ bcnt, int* __restrict__ boff,
                             int NB, float* __restrict__ pooled, int capg,
                             int* __restrict__ sbcnt, int nsb) {
    int t = blockIdx.x * blockDim.x + threadIdx.x;
    int stride = gridDim.x * blockDim.x;
    for (int i = t; i < NB; i += stride) {
        bcnt[i] = 0;
        if (capg) boff[i] = i * capg;
    }
    for (int i = t; i < nsb; i += stride) sbcnt[i] = 0;
    if (t == 0) pooled[0] = 0.f;
}

// ---------------- Pass 1: partition edges into super-buckets (coalesced) -----
__global__ void __launch_bounds__(256, 4)
part1_kernel(const int* __restrict__ ei, int E, int N,
             int* __restrict__ sbcnt, uint_t* __restrict__ sbdata) {
    __shared__ int hist[NSBMAX];
    __shared__ int loff[NSBMAX];
    __shared__ int lcur[NSBMAX];
    __shared__ int gb[NSBMAX];
    __shared__ uint_t buf[P_CHUNK];
    __shared__ unsigned char sbarr[P_CHUNK];
    int tid = threadIdx.x;
    int NSB = (N + ((1 << SB_SHIFT) - 1)) >> SB_SHIFT;
    for (int i = tid; i < NSB; i += 256) hist[i] = 0;
    __syncthreads();
    int EN = E + N;
    int base = blockIdx.x * P_CHUNK;
    int m = EN - base; if (m > P_CHUNK) m = P_CHUNK;
    int t0 = base + tid * 8;
    int s[8], d[8];
    bool fast = (t0 + 8 <= E) && ((E & 3) == 0);
    if (fast) {
        int4 a = *(const int4*)&ei[t0];
        int4 b = *(const int4*)&ei[t0 + 4];
        s[0]=a.x; s[1]=a.y; s[2]=a.z; s[3]=a.w; s[4]=b.x; s[5]=b.y; s[6]=b.z; s[7]=b.w;
        int4 c = *(const int4*)&ei[E + t0];
        int4 e2 = *(const int4*)&ei[E + t0 + 4];
        d[0]=c.x; d[1]=c.y; d[2]=c.z; d[3]=c.w; d[4]=e2.x; d[5]=e2.y; d[6]=e2.z; d[7]=e2.w;
    } else {
#pragma unroll
        for (int r = 0; r < 8; ++r) {
            int t = t0 + r;
            if (t < EN) {
                if (t < E) { s[r] = ei[t]; d[r] = ei[E + t]; }
                else       { s[r] = d[r] = t - E; }
            } else d[r] = -1;
        }
    }
#pragma unroll
    for (int r = 0; r < 8; ++r)
        if (d[r] >= 0) atomicAdd(&hist[d[r] >> SB_SHIFT], 1);
    __syncthreads();
    if (tid < 64) {
        int v = (tid < NSB) ? hist[tid] : 0;
        int e = v;
#pragma unroll
        for (int o = 1; o < 64; o <<= 1) {
            int u = __shfl_up(e, o, 64);
            if (tid >= o) e += u;
        }
        e -= v; // exclusive prefix
        if (tid < NSB) {
            loff[tid] = e;
            lcur[tid] = e;
            gb[tid] = v ? atomicAdd(&sbcnt[tid], v) : 0;
        }
    }
    __syncthreads();
#pragma unroll
    for (int r = 0; r < 8; ++r)
        if (d[r] >= 0) {
            int sb = d[r] >> SB_SHIFT;
            int pos = atomicAdd(&lcur[sb], 1);
            buf[pos] = ((uint_t)s[r] << SB_SHIFT) | (uint_t)(d[r] & ((1 << SB_SHIFT) - 1));
            sbarr[pos] = (unsigned char)sb;
        }
    __syncthreads();
    for (int i = tid; i < m; i += 256) {
        int sb = sbarr[i];
        int idx = gb[sb] + (i - loff[sb]);
        if (idx < SBCAP)
            sbdata[(size_t)sb * SBCAP + idx] = buf[i];
    }
}

// ---------------- Pass 2: scatter within SB to final pk buckets (coalesced) --
__global__ void __launch_bounds__(256, 4)
part2_kernel(const uint_t* __restrict__ sbdata, const int* __restrict__ sbcnt,
             int* __restrict__ bcnt, const int* __restrict__ boff,
             uint_t* __restrict__ pk) {
    __shared__ int hist[64];
    __shared__ int loff[64];
    __shared__ int lcur[64];
    __shared__ int gb[64];
    __shared__ uint_t buf[P_CHUNK];
    int tid = threadIdx.x;
    int sb = blockIdx.x / BPS;
    int base = (blockIdx.x % BPS) * P_CHUNK;
    int cnt = sbcnt[sb];
    if (cnt > SBCAP) cnt = SBCAP;
    if (base >= cnt) return;
    int m = cnt - base; if (m > P_CHUNK) m = P_CHUNK;
    if (tid < 64) hist[tid] = 0;
    __syncthreads();
    const uint_t* src = sbdata + (size_t)sb * SBCAP + base;
    uint_t v[8];
#pragma unroll
    for (int r = 0; r < 8; ++r) {
        int i = tid + r * 256; // coalesced strided read
        if (i < m) {
            v[r] = src[i];
            atomicAdd(&hist[(v[r] >> 5) & 63], 1);
        }
    }
    __syncthreads();
    if (tid < 64) {
        int c = hist[tid];
        int e = c;
#pragma unroll
        for (int o = 1; o < 64; o <<= 1) {
            int u = __shfl_up(e, o, 64);
            if (tid >= o) e += u;
        }
        e -= c;
        loff[tid] = e;
        lcur[tid] = e;
        int bucket = (sb << 6) + tid;
        gb[tid] = c ? (boff[bucket] + atomicAdd(&bcnt[bucket], c)) : 0;
    }
    __syncthreads();
#pragma unroll
    for (int r = 0; r < 8; ++r) {
        int i = tid + r * 256;
        if (i < m) {
            int lb = (v[r] >> 5) & 63;
            int pos = atomicAdd(&lcur[lb], 1);
            buf[pos] = v[r];
        }
    }
    __syncthreads();
    for (int i = tid; i < m; i += 256) {
        uint_t u = buf[i];
        int lb = (u >> 5) & 63;
        int idx = gb[lb] + (i - loff[lb]);
        pk[idx] = ((u >> SB_SHIFT) << SHIFT) | (u & (BW - 1));
    }
}

// ---- exact-CSR fallback path (used only when ws_size too small for static) --
__global__ void bhist_kernel(const int* __restrict__ ei, int E, int N,
                             int* __restrict__ bcnt, int NB) {
    __shared__ int h[NBMAX];
    int tid = threadIdx.x;
    for (int i = tid; i < NB; i += 256) h[i] = 0;
    __syncthreads();
    int EN = E + N;
    int chunk = (EN + gridDim.x - 1) / gridDim.x;
    int e0 = blockIdx.x * chunk;
    int e1 = e0 + chunk; if (e1 > EN) e1 = EN;
    for (int t = e0 + tid; t < e1; t += 256) {
        int d = (t < E) ? ei[E + t] : (t - E);
        atomicAdd(&h[d >> SHIFT], 1);
    }
    __syncthreads();
    for (int i = tid; i < NB; i += 256)
        if (h[i]) atomicAdd(&bcnt[i], h[i]);
}

__global__ void bscan_kernel(const int* __restrict__ bcnt, int NB,
                             int* __restrict__ boff, int* __restrict__ bcur) {
    int lane = threadIdx.x; // 0..63
    int chunk = (NB + 63) >> 6;
    int lo = lane * chunk;
    int hi = lo + chunk; if (hi > NB) hi = NB;
    int sum = 0;
    for (int i = lo; i < hi; ++i) sum += bcnt[i];
    int e = sum;
#pragma unroll
    for (int o = 1; o < 64; o <<= 1) {
        int v = __shfl_up(e, o, 64);
        if (lane >= o) e += v;
    }
    e -= sum;
    int run = e;
    for (int i = lo; i < hi; ++i) {
        int c = bcnt[i];
        boff[i] = run;
        bcur[i] = run;
        run += c;
    }
}

__global__ void bscat_kernel(const int* __restrict__ ei, int E, int N,
                             int* __restrict__ bcur, uint_t* __restrict__ pk, int NB) {
    __shared__ int lh[NBMAX];
    __shared__ int lc[NBMAX];
    int tid = threadIdx.x;
    for (int i = tid; i < NB; i += 256) lh[i] = 0;
    __syncthreads();
    int EN = E + N;
    int chunk = (EN + gridDim.x - 1) / gridDim.x;
    int e0 = blockIdx.x * chunk;
    int e1 = e0 + chunk; if (e1 > EN) e1 = EN;
    for (int t = e0 + tid; t < e1; t += 256) {
        int d = (t < E) ? ei[E + t] : (t - E);
        atomicAdd(&lh[d >> SHIFT], 1);
    }
    __syncthreads();
    for (int i = tid; i < NB; i += 256) {
        int c = lh[i];
        lc[i] = c ? atomicAdd(&bcur[i], c) : 0;
    }
    __syncthreads();
    for (int t = e0 + tid; t < e1; t += 256) {
        int s, d;
        if (t < E) { s = ei[t]; d = ei[E + t]; } else { s = d = t - E; }
        int pos = atomicAdd(&lc[d >> SHIFT], 1);
        pk[pos] = ((uint_t)s << SHIFT) | (uint_t)(d & (BW - 1));
    }
}

// ---------------- Fused layer-1 edge pass + layer-2 GEMM ---------------------
// Gather body is the R3/R8-proven one (per-bucket launch, 4 slots, depth-1
// prefetch). Differences vs R8:
//  (a) a1 rows stay in LDS (no o1 materialization, -51 MB traffic),
//  (b) epilogue computes h2 = elu(a1+b1)@W2 and emits rec={packAB(vs), g.Wr}
//      + ed2 directly (gemm2 kernel removed),
//  (c) sorted src list written back over pk + per-dst CSR (loffg/ldegg) so
//      edge2 needs no LDS build at all.
__global__ void __launch_bounds__(256, 8)
edge1_fused(const int* __restrict__ bcnt, const int* __restrict__ boff,
            uint_t* __restrict__ pk,
            const uint_t* __restrict__ sp, const float* __restrict__ ed,
            const ushort_t* __restrict__ h1,
            const float* __restrict__ b1, const float* __restrict__ W2,
            const float* __restrict__ a_src2, const float* __restrict__ a_dst2,
            const float* __restrict__ Wr,
            uint2* __restrict__ rec, float* __restrict__ ed2,
            int* __restrict__ loffg, int* __restrict__ ldegg, int N) {
    int b = blockIdx.x;
    int d0 = b << SHIFT;
    int cnt = bcnt[b];
    int gbase = boff[b];
    int tid = threadIdx.x;
    int wv = tid >> 6;
    int L = tid & 63;
    int q = L >> 4;           // edge slot 0..3
    int c4 = (L & 15) << 2;   // channel base
    int hL = (L & 15) >> 1;   // head of channels c4..c4+3
    __shared__ int ldeg[BW], loff[BW], lcur[BW];
    __shared__ int lsrc[CAPL];
    __shared__ float a1s[BW][F1];   // 8 KB: this bucket's aggregated rows
    if (cnt <= CAPL) {
        if (tid < BW) ldeg[tid] = 0;
        __syncthreads();
        for (int k = tid; k < cnt; k += 256) atomicAdd(&ldeg[pk[gbase + k] & (BW - 1)], 1);
        __syncthreads();
        if (tid < BW) {
            int v = ldeg[tid];
            int e = v;
#pragma unroll
            for (int o = 1; o < BW; o <<= 1) {
                int u = __shfl_up(e, o, 64);
                if (tid >= o) e += u;
            }
            e -= v;
            loff[tid] = e;
            lcur[tid] = e;
        }
        __syncthreads();
        for (int k = tid; k < cnt; k += 256) {
            uint_t v = pk[gbase + k];
            int pos = atomicAdd(&lcur[v & (BW - 1)], 1);
            lsrc[pos] = (int)(v >> SHIFT);
        }
        __syncthreads();
        // writeback for edge2: pk becomes the dst-sorted src list; per-dst CSR
        for (int k = tid; k < cnt; k += 256) pk[gbase + k] = (uint_t)lsrc[k];
        if (tid < BW) {
            loffg[d0 + tid] = loff[tid];
            ldegg[d0 + tid] = ldeg[tid];
        }
        for (int ld = wv * 8; ld < wv * 8 + 8; ++ld) {
            int d = d0 + ld;
            if (d >= N) break;
            int st = loff[ld], en = st + ldeg[ld];
            float edv = ed[d * H1 + hL];
            float Ad = __expf(edv), Bd = __expf(NEG_SLOPE * edv);
            float ax = 0.f, ay = 0.f, az = 0.f, aw = 0.f, wsum = 0.f;
            uint_t U0, U1; uint2 V0, V1;
            {
                int i0 = st + q, i1 = st + 4 + q;
                bool ok0 = i0 < en, ok1 = i1 < en;
                int s0 = lsrc[ok0 ? i0 : st];   // st valid: self-loop => en>st
                int s1 = lsrc[ok1 ? i1 : st];
                uint_t u0 = sp[s0 * H1 + hL];
                uint_t u1 = sp[s1 * H1 + hL];
                V0 = *(const uint2*)(h1 + ((size_t)s0 << 6) + c4);
                V1 = *(const uint2*)(h1 + ((size_t)s1 << 6) + c4);
                U0 = ok0 ? u0 : 0u;
                U1 = ok1 ? u1 : 0u;
            }
            for (int k = st; k < en; k += 8) {
                uint_t N0, N1; uint2 P0, P1;
                {
                    int i0 = k + 8 + q, i1 = k + 12 + q;
                    bool ok0 = i0 < en, ok1 = i1 < en;
                    int s0 = lsrc[ok0 ? i0 : st];
                    int s1 = lsrc[ok1 ? i1 : st];
                    uint_t u0 = sp[s0 * H1 + hL];
                    uint_t u1 = sp[s1 * H1 + hL];
                    P0 = *(const uint2*)(h1 + ((size_t)s0 << 6) + c4);
                    P1 = *(const uint2*)(h1 + ((size_t)s1 << 6) + c4);
                    N0 = ok0 ? u0 : 0u;
                    N1 = ok1 ? u1 : 0u;
                }
                float w0 = fmaxf(LO16(U0) * Ad, HI16(U0) * Bd);
                float w1 = fmaxf(LO16(U1) * Ad, HI16(U1) * Bd);
                ax = fmaf(w0, LO16(V0.x), ax);
                ay = fmaf(w0, HI16(V0.x), ay);
                az = fmaf(w0, LO16(V0.y), az);
                aw = fmaf(w0, HI16(V0.y), aw);
                ax = fmaf(w1, LO16(V1.x), ax);
                ay = fmaf(w1, HI16(V1.x), ay);
                az = fmaf(w1, LO16(V1.y), az);
                aw = fmaf(w1, HI16(V1.y), aw);
                wsum += w0 + w1;
                U0 = N0; U1 = N1; V0 = P0; V1 = P1;
            }
            FOLDQ4(ax); FOLDQ4(ay); FOLDQ4(az); FOLDQ4(aw); FOLDQ4(wsum);
            if (q == 0) {
                float inv = 1.f / wsum;
                a1s[ld][c4 + 0] = ax * inv;
                a1s[ld][c4 + 1] = ay * inv;
                a1s[ld][c4 + 2] = az * inv;
                a1s[ld][c4 + 3] = aw * inv;
            }
        }
    } else {
        // statistically unreachable fallback: masked whole-bucket scan
        for (int ld = wv * 8; ld < wv * 8 + 8; ++ld) {
            int d = d0 + ld;
            if (d >= N) break;
            float edv = ed[d * H1 + hL];
            float Ad = __expf(edv), Bd = __expf(NEG_SLOPE * edv);
            float ax = 0.f, ay = 0.f, az = 0.f, aw = 0.f, wsum = 0.f;
            for (int k0 = 0; k0 < cnt; k0 += 4) {
                int idx = k0 + q;
                bool ok = idx < cnt;
                uint_t v = pk[gbase + (ok ? idx : 0)];
                int s = (int)(v >> SHIFT);
                bool m = ok && ((int)(v & (BW - 1)) == ld);
                uint_t u = sp[(uint_t)s * H1 + hL];
                float w = m ? fmaxf(LO16(u) * Ad, HI16(u) * Bd) : 0.f;
                uint2 hv = *(const uint2*)(h1 + ((size_t)s << 6) + c4);
                ax = fmaf(w, LO16(hv.x), ax);
                ay = fmaf(w, HI16(hv.x), ay);
                az = fmaf(w, LO16(hv.y), az);
                aw = fmaf(w, HI16(hv.y), aw);
                wsum += w;
            }
            FOLDQ4(ax); FOLDQ4(ay); FOLDQ4(az); FOLDQ4(aw); FOLDQ4(wsum);
            if (q == 0) {
                float inv = 1.f / wsum;
                a1s[ld][c4 + 0] = ax * inv;
                a1s[ld][c4 + 1] = ay * inv;
                a1s[ld][c4 + 2] = az * inv;
                a1s[ld][c4 + 3] = aw * inv;
            }
        }
    }
    // -------- fused layer-2 GEMM epilogue (replaces gemm2_kernel) --------
    int nd = N - d0; if (nd > BW) nd = BW;  // valid dsts in this bucket
    __syncthreads();
    for (int i = tid; i < BW * F1; i += 256) {
        int dd = i >> 6;
        if (dd < nd) {
            int k = i & 63;
            float v = a1s[dd][k] + b1[k];
            a1s[dd][k] = v > 0.f ? v : expm1f(v); // ELU
        }
    }
    __syncthreads();
    int half = tid >> 5, j = tid & 31;
#pragma unroll
    for (int pass = 0; pass < 4; ++pass) {
        int ld2 = half + (pass << 3);
        if (ld2 < nd) {
            float acc = 0.f;
#pragma unroll
            for (int k = 0; k < F1; ++k) acc = fmaf(a1s[ld2][k], W2[k * F2 + j], acc);
            float vs = acc * a_src2[j];
            float vd = acc * a_dst2[j];
            float vg = acc * Wr[j];
#pragma unroll
            for (int off = 16; off >= 1; off >>= 1) {
                vs += __shfl_down(vs, off, 32);
                vd += __shfl_down(vd, off, 32);
                vg += __shfl_down(vg, off, 32);
            }
            if (j == 0) {
                int d = d0 + ld2;
                uint2 r; r.x = packAB(vs); r.y = __float_as_uint(vg);
                rec[d] = r;
                ed2[d] = vd;
            }
        }
    }
}

// ---------------- Layer-2 edge pass: pure streaming gather -------------------
// pk holds dst-sorted src lists (written by edge1_fused); loffg/ldegg give the
// per-dst CSR. No LDS build: coalesced pk reads + 8-B rec gathers (800 KB,
// L2-resident). Fallback buckets (cnt > CAPL) kept raw -> masked scan.
__global__ void __launch_bounds__(256, 8)
edge2_gather(const int* __restrict__ bcnt, const int* __restrict__ boff,
             const uint_t* __restrict__ pk,
             const int* __restrict__ loffg, const int* __restrict__ ldegg,
             const uint2* __restrict__ rec, const float* __restrict__ ed2,
             const float* __restrict__ b2, const float* __restrict__ Wr,
             float* __restrict__ pooled, int N) {
    int b = blockIdx.x;
    int d0 = b << SHIFT;
    int cnt = bcnt[b];
    int gbase = boff[b];
    int tid = threadIdx.x;
    int wv = tid >> 6;
    int L = tid & 63;
    __shared__ float ls[4];
    float t0 = (L < F2) ? b2[L] * Wr[L] : 0.f;
    FOLD64(t0);
    float b2w = t0;          // dot(b2, Wr), identical on all lanes
    float part = 0.f;
    if (cnt <= CAPL) {
        for (int ld = wv * 8; ld < wv * 8 + 8; ++ld) {
            int d = d0 + ld;
            if (d >= N) break;
            int st = gbase + loffg[d];
            int dg = ldegg[d];
            float edv = ed2[d];
            float Ad = __expf(edv), Bd = __expf(NEG_SLOPE * edv);
            float acc = 0.f, wsm = 0.f;
            for (int k = 0; k < dg; k += 64) {
                int i = k + L;
                bool ok = i < dg;
                int s = (int)pk[st + (ok ? i : 0)];
                uint2 r = rec[s];
                float w = ok ? fmaxf(LO16(r.x) * Ad, HI16(r.x) * Bd) : 0.f;
                acc = fmaf(w, __uint_as_float(r.y), acc);
                wsm += w;
            }
            FOLD64(acc); FOLD64(wsm);
            part += acc / wsm + b2w;   // FOLD64 left totals in EVERY lane
        }
    } else {
        // raw-pk masked scan (pk left in original packed format for this bucket)
        for (int ld = wv * 8; ld < wv * 8 + 8; ++ld) {
            int d = d0 + ld;
            if (d >= N) break;
            float edv = ed2[d];
            float Ad = __expf(edv), Bd = __expf(NEG_SLOPE * edv);
            float acc = 0.f, wsm = 0.f;
            for (int k0 = 0; k0 < cnt; k0 += 64) {
                int i = k0 + L;
                bool ok = i < cnt;
                uint_t v = pk[gbase + (ok ? i : 0)];
                int s = (int)(v >> SHIFT);
                bool mm = ok && ((int)(v & (BW - 1)) == ld);
                uint2 r = rec[s];
                float w = mm ? fmaxf(LO16(r.x) * Ad, HI16(r.x) * Bd) : 0.f;
                acc = fmaf(w, __uint_as_float(r.y), acc);
                wsm += w;
            }
            FOLD64(acc); FOLD64(wsm);
            part += acc / wsm + b2w;
        }
    }
    // part is LANE-UNIFORM (FOLD64 totals) -- take lane 0 only.
    // R9 BUG: an extra 64-lane shfl_down sum here counted each dst 64x.
    if (L == 0) ls[wv] = part;
    __syncthreads();
    if (tid == 0) atomicAdd(pooled, ls[0] + ls[1] + ls[2] + ls[3]);
}

__global__ void final_kernel(const float* __restrict__ pooled, const float* __restrict__ br,
                             float* __restrict__ out) {
    if (threadIdx.x == 0 && blockIdx.x == 0) out[0] = pooled[0] + br[0];
}

static inline size_t al128(size_t v) { return (v + 127) & ~(size_t)127; }

extern "C" void kernel_launch(void* const* d_in, const int* in_sizes, int n_in,
                              void* d_out, int out_size, void* d_ws, size_t ws_size,
                              hipStream_t stream) {
    const float* x    = (const float*)d_in[0];
    const int*   ei   = (const int*)d_in[1];
    const float* W1   = (const float*)d_in[2];
    const float* a_s1 = (const float*)d_in[3];
    const float* a_d1 = (const float*)d_in[4];
    const float* b1   = (const float*)d_in[5];
    const float* W2   = (const float*)d_in[6];
    const float* a_s2 = (const float*)d_in[7];
    const float* a_d2 = (const float*)d_in[8];
    const float* b2   = (const float*)d_in[9];
    const float* Wr   = (const float*)d_in[10];
    const float* br   = (const float*)d_in[11];
    float* out = (float*)d_out;

    int N = in_sizes[0] / FIN;
    int E = in_sizes[1] / 2;
    size_t n = (size_t)N;
    int NB = (N + BW - 1) >> SHIFT;
    int NSB = (N + ((1 << SB_SHIFT) - 1)) >> SB_SHIFT;

    // workspace layout (bytes); all hot arrays 128-B aligned.
    // CRITICAL: h1 rows are 128 B and gathered randomly -- h1 base MUST be
    // 128-aligned or every row straddles two cache lines (R4: FETCH +64%).
    // The former o1 region (256N bytes) is now pure scratch: sbdata lives
    // there during part1/part2 (dead after), then rec/ed2/loffg/ldegg are
    // written there by edge1_fused (disjoint lifetimes, overlapping addrs ok).
    char* ws = (char*)d_ws;
    size_t off_scr = 0;                                   // 256N scratch
    size_t off_sp1 = al128(off_scr + n * 256);            // 32N + 32
    size_t off_ed1 = al128(off_sp1 + n * 32 + 32);        // 32N
    size_t off_h1  = al128(off_ed1 + n * 32);             // 128N + 128
    size_t off_pk  = al128(off_h1 + n * 128 + 128);
    uint_t*   sp1  = (uint_t*)(ws + off_sp1);
    float*    ed1  = (float*)(ws + off_ed1);
    ushort_t* h1   = (ushort_t*)(ws + off_h1);
    uint_t*   pk   = (uint_t*)(ws + off_pk);
    size_t pk_static = (size_t)NB * CAP_G * 4;            // ~17.6 MB
    size_t pk_exact  = (size_t)(E + N) * 4;               // ~13.2 MB
    // scratch-region tenants:
    uint_t* sbdata = (uint_t*)(ws + off_scr);             // part1/part2 only
    size_t off_rec  = off_scr;                            // 8*NB*BW
    size_t off_ed2  = al128(off_rec + (size_t)NB * BW * 8);
    size_t off_lofg = al128(off_ed2 + (size_t)NB * BW * 4);
    size_t off_ldgg = al128(off_lofg + (size_t)NB * BW * 4);
    uint2* rec   = (uint2*)(ws + off_rec);
    float* ed2   = (float*)(ws + off_ed2);
    int*   loffg = (int*)(ws + off_lofg);
    int*   ldegg = (int*)(ws + off_ldgg);
    bool use_static = (NSB <= NSBMAX) &&
                      ((size_t)NSB * SBCAP * 4 <= n * 256) &&
                      (off_ldgg + (size_t)NB * BW * 4 <= n * 256) &&
                      (ws_size >= off_pk + pk_static + (size_t)NBMAX * 16 +
                                  (size_t)NSBMAX * 4 + 128);
    char* tail = ws + off_pk + (use_static ? pk_static : pk_exact);
    int*      bcnt  = (int*)tail;                         // NBMAX int
    int*      boff  = (int*)(tail + NBMAX * 4);           // NBMAX int
    int*      bcur  = (int*)(tail + NBMAX * 8);           // NBMAX int
    int*      sbcnt = (int*)(tail + NBMAX * 12);          // NSBMAX int
    float*  pooled  = (float*)(tail + NBMAX * 12 + NSBMAX * 4); // 1 f32

    zerob_kernel<<<8, 256, 0, stream>>>(bcnt, boff, NB, pooled,
                                        use_static ? CAP_G : 0, sbcnt, NSB);
    if (use_static) {
        int EN = E + N;
        int G1 = (EN + P_CHUNK - 1) / P_CHUNK;
        part1_kernel<<<G1, 256, 0, stream>>>(ei, E, N, sbcnt, sbdata);
        part2_kernel<<<NSB * BPS, 256, 0, stream>>>(sbdata, sbcnt, bcnt, boff, pk);
        gemm1_kernel<<<(N + 15) / 16, 256, 0, stream>>>(x, W1, a_s1, a_d1, h1, sp1, ed1, N);
    } else {
        gemm1_kernel<<<(N + 15) / 16, 256, 0, stream>>>(x, W1, a_s1, a_d1, h1, sp1, ed1, N);
        bhist_kernel<<<256, 256, 0, stream>>>(ei, E, N, bcnt, NB);
        bscan_kernel<<<1, 64, 0, stream>>>(bcnt, NB, boff, bcur);
        bscat_kernel<<<256, 256, 0, stream>>>(ei, E, N, bcur, pk, NB);
    }
    edge1_fused<<<NB, 256, 0, stream>>>(bcnt, boff, pk, sp1, ed1, h1,
                                        b1, W2, a_s2, a_d2, Wr,
                                        rec, ed2, loffg, ldegg, N);
    edge2_gather<<<NB, 256, 0, stream>>>(bcnt, boff, pk, loffg, ldegg,
                                         rec, ed2, b2, Wr, pooled, N);
    final_kernel<<<1, 64, 0, stream>>>(pooled, br, out);
}